// Round 5
// baseline (460.958 us; speedup 1.0000x reference)
//
#include <hip/hip_runtime.h>

// GatedMetaFusion R9.
//   transpose_w8: W^T bf16 x8 + zero counts + zero ticket
//   prep_hist_scan: A2/M2/M1 MFMA prep + histogram blocks + LAST-BLOCK prefix scan
//     (device-scope ticket; scan launch eliminated)
//   fill: packed 16B edge records {src, evec0..2} in CSR order
//   edge (grid = M): meta-psum gathers hoisted BEFORE the MFMA (latency hidden)
//   fused_node: double-buffered LDS (Xa/Xb) -> 4 barriers instead of 7;
//     M1 gather issued before MFMA1, SUM gather before MFMA2 (cold-load hiding).
//
// MFMA 16x16x32 bf16 layouts (verified): A[m=lane&15][k=quad*8+j],
// B from W^T row-major 16B/lane, C/D: col=lane&15, row=quad*4+reg.

typedef short bf16x8 __attribute__((ext_vector_type(8)));
typedef float f32x4  __attribute__((ext_vector_type(4)));

#define XS_PAD 136   // bf16 row stride (272B, 16B-aligned)

__device__ __forceinline__ unsigned short f2bf(float f){
  union { float f; unsigned u; } v; v.f = f;
  return (unsigned short)((v.u + 0x7FFFu + ((v.u >> 16) & 1u)) >> 16);
}
__device__ __forceinline__ unsigned pack2(float a, float b){
  return (unsigned)f2bf(a) | ((unsigned)f2bf(b) << 16);
}

__device__ __forceinline__ void mfma_layer(const unsigned short* Xs,
                                           const bf16x8 (&B)[2][4],
                                           int lane, f32x4 (&acc)[4][2]) {
  const int lcol = lane & 15, quad = lane >> 4;
  #pragma unroll
  for (int rg = 0; rg < 4; ++rg) {
    bf16x8 A[4];
    const unsigned short* ab = Xs + (rg*16 + lcol)*XS_PAD + quad*8;
    #pragma unroll
    for (int kk = 0; kk < 4; ++kk) A[kk] = *(const bf16x8*)(ab + kk*32);
    #pragma unroll
    for (int ctl = 0; ctl < 2; ++ctl)
      #pragma unroll
      for (int kk = 0; kk < 4; ++kk)
        acc[rg][ctl] = __builtin_amdgcn_mfma_f32_16x16x32_bf16(
            A[kk], B[ctl][kk], acc[rg][ctl], 0, 0, 0);
  }
}

__device__ __forceinline__ void load_bfrags(const unsigned short* __restrict__ Wt,
                                            int wave, int lane, bf16x8 (&B)[2][4]) {
  const int lcol = lane & 15, quad = lane >> 4;
  #pragma unroll
  for (int ctl = 0; ctl < 2; ++ctl) {
    int col = (wave*2 + ctl)*16 + lcol;
    #pragma unroll
    for (int kk = 0; kk < 4; ++kk)
      B[ctl][kk] = *(const bf16x8*)(Wt + (size_t)col*128 + kk*32 + quad*8);
  }
}

__device__ __forceinline__ void zero_acc(f32x4 (&acc)[4][2]) {
  #pragma unroll
  for (int rg = 0; rg < 4; ++rg)
    #pragma unroll
    for (int ctl = 0; ctl < 2; ++ctl) {
      acc[rg][ctl][0]=0.f; acc[rg][ctl][1]=0.f;
      acc[rg][ctl][2]=0.f; acc[rg][ctl][3]=0.f;
    }
}

// ---------------- 8-slab W^T bf16 prep + zero counts/ticket ----------------
struct WPtrs { const float* s[8]; };
__global__ __launch_bounds__(256) void transpose_w8(WPtrs p,
                                                    unsigned short* __restrict__ dstbase,
                                                    int* __restrict__ counts,
                                                    int* __restrict__ ticket, int M) {
  int slab = blockIdx.x >> 4, blk = blockIdx.x & 15;
  const float* W = p.s[slab];
  unsigned short* Wt = dstbase + (size_t)slab*16384;
  int c  = blk*8 + (threadIdx.x >> 5);
  int k0 = (threadIdx.x & 31) * 4;
  unsigned short o[4];
  #pragma unroll
  for (int j = 0; j < 4; ++j) o[j] = f2bf(W[(size_t)(k0 + j)*128 + c]);
  *(uint2*)(Wt + (size_t)c*128 + k0) =
      make_uint2((unsigned)o[0] | ((unsigned)o[1] << 16),
                 (unsigned)o[2] | ((unsigned)o[3] << 16));
  int tid = blockIdx.x*256 + threadIdx.x;
  int tot = gridDim.x*256;
  for (int i = tid; i < M; i += tot) counts[i] = 0;
  if (tid == 0) *ticket = 0;
}

// --- prep (A2/M2/M1) + hist blocks + LAST-BLOCK prefix scan (ticket) ---
__global__ __launch_bounds__(256) void prep_hist_scan(
    const float* __restrict__ res, const float* __restrict__ meta,
    const unsigned short* __restrict__ WAt, const unsigned short* __restrict__ WBt,
    const unsigned short* __restrict__ WCt, const float* __restrict__ b1,
    float* __restrict__ A2, float* __restrict__ M2, float* __restrict__ M1,
    int mrows, int nbPrep,
    const int* __restrict__ dst, int* __restrict__ counts, int E,
    int* __restrict__ ticket, int nbHist,
    int* __restrict__ row_start, int* __restrict__ cursor, int M) {
  const int t = threadIdx.x;
  if ((int)blockIdx.x >= nbPrep) {              // histogram portion of the grid
    int e = ((int)blockIdx.x - nbPrep)*256 + t;
    if (e < E) atomicAdd(&counts[dst[e]], 1);
    __threadfence();
    __syncthreads();                            // all atomics issued + fenced
    __shared__ int lastFlag;
    if (t == 0) {
      int old = __hip_atomic_fetch_add(ticket, 1, __ATOMIC_ACQ_REL,
                                       __HIP_MEMORY_SCOPE_AGENT);
      lastFlag = (old == nbHist - 1);
    }
    __syncthreads();
    if (!lastFlag) return;
    // last hist block performs the prefix scan (256-wide, chunked)
    __shared__ int ssum[256];
    int carry = 0;
    for (int base = 0; base < M; base += 256) {
      int i = base + t;
      int v = 0;
      if (i < M) v = __hip_atomic_load(&counts[i], __ATOMIC_RELAXED,
                                       __HIP_MEMORY_SCOPE_AGENT);
      ssum[t] = v; __syncthreads();
      for (int off = 1; off < 256; off <<= 1) {
        int x = (t >= off) ? ssum[t-off] : 0; __syncthreads();
        ssum[t] += x; __syncthreads();
      }
      int excl = carry + ssum[t] - v;
      if (i < M) { row_start[i] = excl; cursor[i] = excl; }
      carry += ssum[255];
      __syncthreads();                          // before next chunk overwrites ssum
    }
    return;
  }
  __shared__ __align__(16) unsigned short Xs[64*XS_PAD];
  const int lane = t & 63, wave = t >> 6;
  const int quad = lane >> 4, lcol = lane & 15;
  const int third = nbPrep / 3;
  const int yy = (int)blockIdx.x / third;
  const int bx = (int)blockIdx.x - yy*third;
  const int tile0 = bx * 64;
  const float* X = (yy == 0) ? res : meta;
  const unsigned short* Wt = (yy == 0) ? WAt : (yy == 1) ? WBt : WCt;
  float* Y = (yy == 0) ? A2 : (yy == 1) ? M2 : M1;
  bf16x8 B[2][4];
  load_bfrags(Wt, wave, lane, B);
  #pragma unroll
  for (int i = 0; i < 8; ++i) {
    int f = t + i*256, row = f >> 5, c4 = f & 31;
    int gr = tile0 + row;
    float4 v = make_float4(0.f,0.f,0.f,0.f);
    if (gr < mrows) v = *(const float4*)(X + (size_t)gr*128 + c4*4);
    *(uint2*)(Xs + row*XS_PAD + c4*4) = make_uint2(pack2(v.x,v.y), pack2(v.z,v.w));
  }
  __syncthreads();
  f32x4 acc[4][2]; zero_acc(acc);
  mfma_layer(Xs, B, lane, acc);
  #pragma unroll
  for (int rg = 0; rg < 4; ++rg)
    #pragma unroll
    for (int ctl = 0; ctl < 2; ++ctl) {
      int col = (wave*2 + ctl)*16 + lcol;
      float badd = 0.f;
      if (yy == 0) badd = b1[col];              // fold g2b1 into A2
      #pragma unroll
      for (int reg = 0; reg < 4; ++reg) {
        int gr = tile0 + rg*16 + quad*4 + reg;
        if (gr < mrows) Y[(size_t)gr*128 + col] = acc[rg][ctl][reg] + badd;
      }
    }
}

// -------- fill: packed 16B records {src, evec0..2} in CSR order --------
__global__ void fill_kernel(const int* __restrict__ dst, const int* __restrict__ src,
                            const float* __restrict__ evec, int* __restrict__ cursor,
                            float4* __restrict__ edata, int E) {
  int e = blockIdx.x*256 + threadIdx.x;
  if (e < E) {
    int p = atomicAdd(&cursor[dst[e]], 1);
    edata[p] = make_float4(__int_as_float(src[e]),
                           evec[(size_t)e*3], evec[(size_t)e*3+1], evec[(size_t)e*3+2]);
  }
}

// ---------------- edge phase: grid = M, one block per node ----------------
__global__ __launch_bounds__(256) void edge_mfma(
    const float* __restrict__ A2, const float* __restrict__ M2,
    const float* __restrict__ meta, const float4* __restrict__ edata,
    const int* __restrict__ row_start, const int* __restrict__ counts,
    const float* __restrict__ g2W1full,
    const unsigned short* __restrict__ W2t, const float* __restrict__ b2,
    float* __restrict__ SUM) {
  const int n = blockIdx.x;
  const int cnt = counts[n];
  if (cnt <= 0) return;                    // SUM[n] never read when count==0
  const int rs = row_start[n];

  __shared__ __align__(16) unsigned short Xh[64*XS_PAD];
  __shared__ int srcl[64];
  __shared__ float evl[192];
  const int t = threadIdx.x, lane = t & 63, wave = t >> 6;
  const int quad = lane >> 4, lcol = lane & 15;
  const int c0 = (t & 31) * 4, rbase = t >> 5;

  // prefetch first tile's records — one coalesced float4 per edge
  float4 ed = make_float4(0.f,0.f,0.f,0.f);
  if (t < 64 && t < cnt) ed = edata[rs + t];

  bf16x8 BW2[2][4];
  load_bfrags(W2t, wave, lane, BW2);
  float4 base = *(const float4*)(A2 + (size_t)n*128 + c0);   // g2b1 pre-folded
  float4 w0 = *(const float4*)(g2W1full + 256*128 + c0);
  float4 w1 = *(const float4*)(g2W1full + 257*128 + c0);
  float4 w2 = *(const float4*)(g2W1full + 258*128 + c0);
  const int colA = wave*32 + lcol, colB = colA + 16;
  const float b2A = b2[colA], b2B = b2[colB];
  float psA = 0.f, psB = 0.f;

  for (int t0 = 0; t0 < cnt; t0 += 64) {
    if (t0) __syncthreads();               // prev tile fully consumed
    if (t < 64) {
      srcl[t] = __float_as_int(ed.x);
      evl[3*t] = ed.y; evl[3*t+1] = ed.z; evl[3*t+2] = ed.w;
      int idx = t0 + 64 + t;               // prefetch next tile
      ed = make_float4(0.f,0.f,0.f,0.f);
      if (idx < cnt) ed = edata[rs + idx];
    }
    __syncthreads();
    // hoist meta-psum gathers: depend only on srcl, hidden under h+MFMA
    float mvA[16], mvB[16];
    #pragma unroll
    for (int rg = 0; rg < 4; ++rg)
      #pragma unroll
      for (int reg = 0; reg < 4; ++reg) {
        int k = rg*4 + reg, rl = rg*16 + quad*4 + reg;
        int s = srcl[rl];                  // s==0 for pad rows: loads valid
        mvA[k] = meta[(size_t)s*128 + colA];
        mvB[k] = meta[(size_t)s*128 + colB];
      }
    #pragma unroll
    for (int i = 0; i < 8; ++i) {          // h = relu(base + M2[src] + evec.Wc)
      int row = rbase + 8*i;
      float4 h = make_float4(0.f,0.f,0.f,0.f);
      if (t0 + row < cnt) {
        int s = srcl[row];
        float4 m = *(const float4*)(M2 + (size_t)s*128 + c0);
        float e0 = evl[3*row], e1 = evl[3*row+1], e2 = evl[3*row+2];
        h.x = fmaxf(base.x + m.x + e0*w0.x + e1*w1.x + e2*w2.x, 0.f);
        h.y = fmaxf(base.y + m.y + e0*w0.y + e1*w1.y + e2*w2.y, 0.f);
        h.z = fmaxf(base.z + m.z + e0*w0.z + e1*w1.z + e2*w2.z, 0.f);
        h.w = fmaxf(base.w + m.w + e0*w0.w + e1*w1.w + e2*w2.w, 0.f);
      }
      *(uint2*)(Xh + row*XS_PAD + c0) = make_uint2(pack2(h.x,h.y), pack2(h.z,h.w));
    }
    __syncthreads();
    f32x4 acc[4][2]; zero_acc(acc);
    mfma_layer(Xh, BW2, lane, acc);        // g = h @ g2W2
    #pragma unroll
    for (int rg = 0; rg < 4; ++rg)         // psum += (g+b2)*meta[src] (prefetched)
      #pragma unroll
      for (int reg = 0; reg < 4; ++reg) {
        int k = rg*4 + reg, rl = rg*16 + quad*4 + reg;
        if (t0 + rl < cnt) {
          psA += (acc[rg][0][reg] + b2A) * mvA[k];
          psB += (acc[rg][1][reg] + b2B) * mvB[k];
        }
      }
  }
  psA += __shfl_xor(psA, 16, 64); psA += __shfl_xor(psA, 32, 64);
  psB += __shfl_xor(psB, 16, 64); psB += __shfl_xor(psB, 32, 64);
  if (quad == 0) {                         // block owns node n: plain store
    SUM[(size_t)n*128 + colA] = psA;
    SUM[(size_t)n*128 + colB] = psB;
  }
}

// ------- fused node: double-buffered LDS, 4 barriers, hoisted gathers -------
__global__ __launch_bounds__(256) void fused_node(
    const float* __restrict__ res, const float* __restrict__ meta,
    const int* __restrict__ sec_ids, const float* __restrict__ pe,
    const float* __restrict__ g1W1full, const float* __restrict__ M1,
    const unsigned short* __restrict__ g1At,
    const unsigned short* __restrict__ g1W2t, const float* __restrict__ g1b1,
    const float* __restrict__ g1b2,
    const unsigned short* __restrict__ fW1t, const float* __restrict__ fb1v,
    const unsigned short* __restrict__ fW2t, const float* __restrict__ fb2v,
    const float* __restrict__ SUM, const int* __restrict__ counts, int msize,
    float* __restrict__ out, int rows) {
  __shared__ __align__(16) unsigned short Xa[64*XS_PAD];
  __shared__ __align__(16) unsigned short Xb[64*XS_PAD];
  __shared__ int   sids[64];
  __shared__ float pel[192];
  __shared__ float inv[64];
  const int t = threadIdx.x, lane = t & 63, wave = t >> 6;
  const int quad = lane >> 4, lcol = lane & 15;
  const int tile0 = blockIdx.x * 64;
  const int c0 = (t & 31) * 4, rbase = t >> 5;
  const int colA = wave*32 + lcol, colB = colA + 16;

  if (t < 64) {
    int gr = tile0 + t;
    sids[t] = (gr < rows) ? sec_ids[gr] : 0;
    float p0=0.f,p1=0.f,p2=0.f;
    if (gr < rows){ p0=pe[(size_t)gr*3]; p1=pe[(size_t)gr*3+1]; p2=pe[(size_t)gr*3+2]; }
    pel[3*t]=p0; pel[3*t+1]=p1; pel[3*t+2]=p2;
    int c = (gr < rows && gr < msize) ? counts[gr] : 0;
    inv[t] = (c > 0) ? 1.f/(float)c : 0.f;
  }
  bf16x8 BF[2][4];
  load_bfrags(g1At, wave, lane, BF);
  #pragma unroll
  for (int i = 0; i < 8; ++i) {                           // stage res -> Xa
    int row = rbase + 8*i, gr = tile0 + row;
    float4 v = make_float4(0.f,0.f,0.f,0.f);
    if (gr < rows) v = *(const float4*)(res + (size_t)gr*128 + c0);
    *(uint2*)(Xa + row*XS_PAD + c0) = make_uint2(pack2(v.x,v.y), pack2(v.z,v.w));
  }
  __syncthreads();                                        // B1: Xa + sids ready

  // hoist M1 gathers (need sids only) — consumed by h1 epilogue, hide under MFMA1
  float m1A[16], m1B[16];
  #pragma unroll
  for (int rg = 0; rg < 4; ++rg)
    #pragma unroll
    for (int reg = 0; reg < 4; ++reg) {
      int k = rg*4 + reg, row = rg*16 + quad*4 + reg;
      int sid = sids[row];
      m1A[k] = M1[(size_t)sid*128 + colA];
      m1B[k] = M1[(size_t)sid*128 + colB];
    }
  f32x4 acc[4][2]; zero_acc(acc);
  mfma_layer(Xa, BF, lane, acc);                          // res @ g1A
  load_bfrags(g1W2t, wave, lane, BF);
  {
    // h1 = relu(acc + M1[sec] + b1 - pe.Wc)  -> Xb  (no barrier: other buffer)
    const float b1A = g1b1[colA], b1B = g1b1[colB];
    const float wA0 = g1W1full[256*128+colA], wA1 = g1W1full[257*128+colA],
                wA2 = g1W1full[258*128+colA];
    const float wB0 = g1W1full[256*128+colB], wB1 = g1W1full[257*128+colB],
                wB2 = g1W1full[258*128+colB];
    #pragma unroll
    for (int rg = 0; rg < 4; ++rg)
      #pragma unroll
      for (int reg = 0; reg < 4; ++reg) {
        int k = rg*4 + reg, row = rg*16 + quad*4 + reg;
        float p0 = pel[3*row], p1 = pel[3*row+1], p2 = pel[3*row+2];
        float vA = acc[rg][0][reg] + m1A[k] + b1A - p0*wA0 - p1*wA1 - p2*wA2;
        float vB = acc[rg][1][reg] + m1B[k] + b1B - p0*wB0 - p1*wB1 - p2*wB2;
        Xb[row*XS_PAD + colA] = f2bf(fmaxf(vA, 0.f));
        Xb[row*XS_PAD + colB] = f2bf(fmaxf(vB, 0.f));
      }
  }
  __syncthreads();                                        // B2: h1 in Xb ready

  // hoist SUM gathers (HBM-cold): guarded by inv>0, hide under MFMA2
  float sAv[16], sBv[16];
  #pragma unroll
  for (int rg = 0; rg < 4; ++rg)
    #pragma unroll
    for (int reg = 0; reg < 4; ++reg) {
      int k = rg*4 + reg, row = rg*16 + quad*4 + reg, gr = tile0 + row;
      float iv = inv[row];
      sAv[k] = (iv > 0.f) ? SUM[(size_t)gr*128 + colA] : 0.f;
      sBv[k] = (iv > 0.f) ? SUM[(size_t)gr*128 + colB] : 0.f;
    }
  zero_acc(acc);
  mfma_layer(Xb, BF, lane, acc);                          // g = h1 @ g1W2
  load_bfrags(fW1t, wave, lane, BF);
  {
    // fused = res + (g+b2)*meta[sec] + SUM/cnt  -> Xa
    const float b2A = g1b2[colA], b2B = g1b2[colB];
    #pragma unroll
    for (int rg = 0; rg < 4; ++rg)
      #pragma unroll
      for (int reg = 0; reg < 4; ++reg) {
        int k = rg*4 + reg, row = rg*16 + quad*4 + reg, gr = tile0 + row;
        unsigned short oA = 0, oB = 0;
        if (gr < rows) {
          int sid = sids[row];
          float iv = inv[row];
          float gA = acc[rg][0][reg] + b2A, gB = acc[rg][1][reg] + b2B;
          float mA = meta[(size_t)sid*128 + colA], mB = meta[(size_t)sid*128 + colB];
          float rA = res[(size_t)gr*128 + colA],  rB = res[(size_t)gr*128 + colB];
          oA = f2bf(rA + gA*mA + sAv[k]*iv);
          oB = f2bf(rB + gB*mB + sBv[k]*iv);
        }
        Xa[row*XS_PAD + colA] = oA;
        Xa[row*XS_PAD + colB] = oB;
      }
  }
  __syncthreads();                                        // B3: fused in Xa ready
  zero_acc(acc);
  mfma_layer(Xa, BF, lane, acc);                          // fused @ fW1
  load_bfrags(fW2t, wave, lane, BF);
  {
    const float fb1A = fb1v[colA], fb1B = fb1v[colB];
    #pragma unroll
    for (int rg = 0; rg < 4; ++rg)                        // h2 -> Xb
      #pragma unroll
      for (int reg = 0; reg < 4; ++reg) {
        int row = rg*16 + quad*4 + reg;
        Xb[row*XS_PAD + colA] = f2bf(fmaxf(acc[rg][0][reg] + fb1A, 0.f));
        Xb[row*XS_PAD + colB] = f2bf(fmaxf(acc[rg][1][reg] + fb1B, 0.f));
      }
  }
  __syncthreads();                                        // B4: h2 in Xb ready
  zero_acc(acc);
  mfma_layer(Xb, BF, lane, acc);                          // out = h2 @ fW2
  {
    const float fb2A = fb2v[colA], fb2B = fb2v[colB];
    #pragma unroll
    for (int rg = 0; rg < 4; ++rg)                        // direct C-layout store
      #pragma unroll
      for (int reg = 0; reg < 4; ++reg) {
        int gr = tile0 + rg*16 + quad*4 + reg;
        if (gr < rows) {
          out[(size_t)gr*128 + colA] = acc[rg][0][reg] + fb2A;
          out[(size_t)gr*128 + colB] = acc[rg][1][reg] + fb2B;
        }
      }
  }
}

extern "C" void kernel_launch(void* const* d_in, const int* in_sizes, int n_in,
                              void* d_out, int out_size, void* d_ws, size_t ws_size,
                              hipStream_t stream) {
  const float* res     = (const float*)d_in[0];
  const float* meta    = (const float*)d_in[1];
  const int*   sec_ids = (const int*)  d_in[2];
  const float* pe      = (const float*)d_in[3];
  const int*   edge    = (const int*)  d_in[4];
  const float* evec    = (const float*)d_in[5];
  const float* g1W1 = (const float*)d_in[6];
  const float* g1b1 = (const float*)d_in[7];
  const float* g1W2 = (const float*)d_in[8];
  const float* g1b2 = (const float*)d_in[9];
  const float* g2W1 = (const float*)d_in[10];
  const float* g2b1 = (const float*)d_in[11];
  const float* g2W2 = (const float*)d_in[12];
  const float* g2b2 = (const float*)d_in[13];
  const float* fW1  = (const float*)d_in[14];
  const float* fb1  = (const float*)d_in[15];
  const float* fW2  = (const float*)d_in[16];
  const float* fb2  = (const float*)d_in[17];

  const int N = in_sizes[0] / 128;
  const int M = in_sizes[1] / 128;
  const int E = in_sizes[4] / 2;
  const int* src = edge;
  const int* dst = edge + E;

  float* ws = (float*)d_ws;
  float* A2   = ws;                          // M*128
  float* M2   = A2 + (size_t)M*128;          // M*128
  float* M1   = M2 + (size_t)M*128;          // M*128 (meta @ g1B, f32)
  float* SUMb = M1 + (size_t)M*128;          // M*128 (read only when count>0)
  int* counts     = (int*)(SUMb + (size_t)M*128);
  int* row_startp = counts + M;
  int* cursor     = row_startp + M;
  int* ticket     = cursor + M;
  uintptr_t ap = (uintptr_t)(ticket + 4);
  ap = (ap + 15) & ~(uintptr_t)15;
  float4* edata = (float4*)ap;               // E x 16B packed records
  uintptr_t wp = (uintptr_t)(edata + E);
  wp = (wp + 15) & ~(uintptr_t)15;
  unsigned short* Wt = (unsigned short*)wp;  // 8 slabs x 16384
  unsigned short* W_g1A  = Wt + 0*16384;
  unsigned short* W_g1B  = Wt + 1*16384;
  unsigned short* W_g1W2 = Wt + 2*16384;
  unsigned short* W_g2A  = Wt + 3*16384;
  unsigned short* W_g2B  = Wt + 4*16384;
  unsigned short* W_g2W2 = Wt + 5*16384;
  unsigned short* W_fW1  = Wt + 6*16384;
  unsigned short* W_fW2  = Wt + 7*16384;
  float* out = (float*)d_out;

  WPtrs p;
  p.s[0] = g1W1;            p.s[1] = g1W1 + 128*128;  p.s[2] = g1W2;
  p.s[3] = g2W1;            p.s[4] = g2W1 + 128*128;  p.s[5] = g2W2;
  p.s[6] = fW1;             p.s[7] = fW2;

  const int nbMt   = (M + 63) / 64;
  const int nbN    = (N + 63) / 64;
  const int nbE    = (E + 255) / 256;
  const int nbPrep = 3*nbMt;                 // A2, M2, M1 slabs

  // 1: W transposes + zero counts/ticket
  transpose_w8<<<128, 256, 0, stream>>>(p, Wt, counts, ticket, M);
  // 2: A2/M2/M1 prep + histogram + last-block prefix scan
  prep_hist_scan<<<nbPrep + nbE, 256, 0, stream>>>(res, meta, W_g2A, W_g2B, W_g1B,
                                                   g2b1, A2, M2, M1, M, nbPrep,
                                                   dst, counts, E,
                                                   ticket, nbE,
                                                   row_startp, cursor, M);
  // 3: packed CSR edge records
  fill_kernel<<<nbE, 256, 0, stream>>>(dst, src, evec, cursor, edata, E);
  // 4: edge phase — one block per node, no atomics
  edge_mfma<<<M, 256, 0, stream>>>(A2, M2, meta, edata, row_startp, counts,
                                   g2W1, W_g2W2, g2b2, SUMb);
  // 5: fused node path (double-buffered, 4 barriers)
  fused_node<<<nbN, 256, 0, stream>>>(res, meta, sec_ids, pe, g1W1, M1,
                                      W_g1A, W_g1W2, g1b1, g1b2,
                                      W_fW1, fb1, W_fW2, fb2,
                                      SUMb, counts, M, out, N);
}

// Round 6
// 378.285 us; speedup vs baseline: 1.2185x; 1.2185x over previous
//
#include <hip/hip_runtime.h>

// GatedMetaFusion R10 = R8 launch structure + R9's dbuf fused_node + hoisted edge.
//   transpose_w8: W^T bf16 x8 + zero counts
//   prep_and_hist: A2 = res[0:M]@g2A + g2b1, M2 = meta@g2B, M1 = meta@g1B,
//                  + histogram blocks (plain atomics, no fences)
//   scan_all: single-block scan (separate launch — ticket-fused scan was 152us, reverted)
//   fill: packed 16B edge records {src, evec0..2} in CSR order
//   edge (grid = M): meta-psum gathers hoisted BEFORE the MFMA (latency hidden)
//   fused_node: double-buffered LDS (Xa/Xb) -> 4 barriers;
//     M1 gather issued before MFMA1, SUM gather before MFMA2 (cold-load hiding).
//
// MFMA 16x16x32 bf16 layouts (verified): A[m=lane&15][k=quad*8+j],
// B from W^T row-major 16B/lane, C/D: col=lane&15, row=quad*4+reg.

typedef short bf16x8 __attribute__((ext_vector_type(8)));
typedef float f32x4  __attribute__((ext_vector_type(4)));

#define XS_PAD 136   // bf16 row stride (272B, 16B-aligned)

__device__ __forceinline__ unsigned short f2bf(float f){
  union { float f; unsigned u; } v; v.f = f;
  return (unsigned short)((v.u + 0x7FFFu + ((v.u >> 16) & 1u)) >> 16);
}
__device__ __forceinline__ unsigned pack2(float a, float b){
  return (unsigned)f2bf(a) | ((unsigned)f2bf(b) << 16);
}

__device__ __forceinline__ void mfma_layer(const unsigned short* Xs,
                                           const bf16x8 (&B)[2][4],
                                           int lane, f32x4 (&acc)[4][2]) {
  const int lcol = lane & 15, quad = lane >> 4;
  #pragma unroll
  for (int rg = 0; rg < 4; ++rg) {
    bf16x8 A[4];
    const unsigned short* ab = Xs + (rg*16 + lcol)*XS_PAD + quad*8;
    #pragma unroll
    for (int kk = 0; kk < 4; ++kk) A[kk] = *(const bf16x8*)(ab + kk*32);
    #pragma unroll
    for (int ctl = 0; ctl < 2; ++ctl)
      #pragma unroll
      for (int kk = 0; kk < 4; ++kk)
        acc[rg][ctl] = __builtin_amdgcn_mfma_f32_16x16x32_bf16(
            A[kk], B[ctl][kk], acc[rg][ctl], 0, 0, 0);
  }
}

__device__ __forceinline__ void load_bfrags(const unsigned short* __restrict__ Wt,
                                            int wave, int lane, bf16x8 (&B)[2][4]) {
  const int lcol = lane & 15, quad = lane >> 4;
  #pragma unroll
  for (int ctl = 0; ctl < 2; ++ctl) {
    int col = (wave*2 + ctl)*16 + lcol;
    #pragma unroll
    for (int kk = 0; kk < 4; ++kk)
      B[ctl][kk] = *(const bf16x8*)(Wt + (size_t)col*128 + kk*32 + quad*8);
  }
}

__device__ __forceinline__ void zero_acc(f32x4 (&acc)[4][2]) {
  #pragma unroll
  for (int rg = 0; rg < 4; ++rg)
    #pragma unroll
    for (int ctl = 0; ctl < 2; ++ctl) {
      acc[rg][ctl][0]=0.f; acc[rg][ctl][1]=0.f;
      acc[rg][ctl][2]=0.f; acc[rg][ctl][3]=0.f;
    }
}

// ---------------- 8-slab W^T bf16 prep + zero counts ----------------
struct WPtrs { const float* s[8]; };
__global__ __launch_bounds__(256) void transpose_w8(WPtrs p,
                                                    unsigned short* __restrict__ dstbase,
                                                    int* __restrict__ counts, int M) {
  int slab = blockIdx.x >> 4, blk = blockIdx.x & 15;
  const float* W = p.s[slab];
  unsigned short* Wt = dstbase + (size_t)slab*16384;
  int c  = blk*8 + (threadIdx.x >> 5);
  int k0 = (threadIdx.x & 31) * 4;
  unsigned short o[4];
  #pragma unroll
  for (int j = 0; j < 4; ++j) o[j] = f2bf(W[(size_t)(k0 + j)*128 + c]);
  *(uint2*)(Wt + (size_t)c*128 + k0) =
      make_uint2((unsigned)o[0] | ((unsigned)o[1] << 16),
                 (unsigned)o[2] | ((unsigned)o[3] << 16));
  int tid = blockIdx.x*256 + threadIdx.x;
  int tot = gridDim.x*256;
  for (int i = tid; i < M; i += tot) counts[i] = 0;
}

// --- prep (A2 = res[0:M]@g2A + b1, M2 = meta@g2B, M1 = meta@g1B) + hist blocks ---
__global__ __launch_bounds__(256) void prep_and_hist(
    const float* __restrict__ res, const float* __restrict__ meta,
    const unsigned short* __restrict__ WAt, const unsigned short* __restrict__ WBt,
    const unsigned short* __restrict__ WCt, const float* __restrict__ b1,
    float* __restrict__ A2, float* __restrict__ M2, float* __restrict__ M1,
    int mrows, int nbPrep,
    const int* __restrict__ dst, int* __restrict__ counts, int E) {
  if ((int)blockIdx.x >= nbPrep) {              // histogram portion of the grid
    int e = ((int)blockIdx.x - nbPrep)*256 + threadIdx.x;
    if (e < E) atomicAdd(&counts[dst[e]], 1);
    return;
  }
  __shared__ __align__(16) unsigned short Xs[64*XS_PAD];
  const int t = threadIdx.x, lane = t & 63, wave = t >> 6;
  const int quad = lane >> 4, lcol = lane & 15;
  const int third = nbPrep / 3;
  const int yy = (int)blockIdx.x / third;
  const int bx = (int)blockIdx.x - yy*third;
  const int tile0 = bx * 64;
  const float* X = (yy == 0) ? res : meta;
  const unsigned short* Wt = (yy == 0) ? WAt : (yy == 1) ? WBt : WCt;
  float* Y = (yy == 0) ? A2 : (yy == 1) ? M2 : M1;
  bf16x8 B[2][4];
  load_bfrags(Wt, wave, lane, B);
  #pragma unroll
  for (int i = 0; i < 8; ++i) {
    int f = t + i*256, row = f >> 5, c4 = f & 31;
    int gr = tile0 + row;
    float4 v = make_float4(0.f,0.f,0.f,0.f);
    if (gr < mrows) v = *(const float4*)(X + (size_t)gr*128 + c4*4);
    *(uint2*)(Xs + row*XS_PAD + c4*4) = make_uint2(pack2(v.x,v.y), pack2(v.z,v.w));
  }
  __syncthreads();
  f32x4 acc[4][2]; zero_acc(acc);
  mfma_layer(Xs, B, lane, acc);
  #pragma unroll
  for (int rg = 0; rg < 4; ++rg)
    #pragma unroll
    for (int ctl = 0; ctl < 2; ++ctl) {
      int col = (wave*2 + ctl)*16 + lcol;
      float badd = 0.f;
      if (yy == 0) badd = b1[col];              // fold g2b1 into A2
      #pragma unroll
      for (int reg = 0; reg < 4; ++reg) {
        int gr = tile0 + rg*16 + quad*4 + reg;
        if (gr < mrows) Y[(size_t)gr*128 + col] = acc[rg][ctl][reg] + badd;
      }
    }
}

// ---------------- single-block scan (chunked, M<=2048 per chunk) ----------------
__global__ __launch_bounds__(1024) void scan_all(const int* __restrict__ counts,
                                                 int* __restrict__ row_start,
                                                 int* __restrict__ cursor, int M) {
  __shared__ int s[1024];
  __shared__ int carry_s;
  const int t = threadIdx.x;
  if (t == 0) carry_s = 0;
  __syncthreads();
  for (int base = 0; base < M; base += 2048) {
    int i0 = base + 2*t, i1 = i0 + 1;
    int c0 = (i0 < M) ? counts[i0] : 0;
    int c1 = (i1 < M) ? counts[i1] : 0;
    int pair = c0 + c1;
    s[t] = pair; __syncthreads();
    for (int off = 1; off < 1024; off <<= 1) {
      int x = (t >= off) ? s[t-off] : 0; __syncthreads();
      s[t] += x; __syncthreads();
    }
    int carry = carry_s;
    int excl = carry + s[t] - pair;
    if (i0 < M) { row_start[i0] = excl;       cursor[i0] = excl; }
    if (i1 < M) { row_start[i1] = excl + c0;  cursor[i1] = excl + c0; }
    __syncthreads();
    if (t == 1023) carry_s = carry + s[1023];
    __syncthreads();
  }
}

// -------- fill: packed 16B records {src, evec0..2} in CSR order --------
__global__ void fill_kernel(const int* __restrict__ dst, const int* __restrict__ src,
                            const float* __restrict__ evec, int* __restrict__ cursor,
                            float4* __restrict__ edata, int E) {
  int e = blockIdx.x*256 + threadIdx.x;
  if (e < E) {
    int p = atomicAdd(&cursor[dst[e]], 1);
    edata[p] = make_float4(__int_as_float(src[e]),
                           evec[(size_t)e*3], evec[(size_t)e*3+1], evec[(size_t)e*3+2]);
  }
}

// ---------------- edge phase: grid = M, one block per node ----------------
__global__ __launch_bounds__(256) void edge_mfma(
    const float* __restrict__ A2, const float* __restrict__ M2,
    const float* __restrict__ meta, const float4* __restrict__ edata,
    const int* __restrict__ row_start, const int* __restrict__ counts,
    const float* __restrict__ g2W1full,
    const unsigned short* __restrict__ W2t, const float* __restrict__ b2,
    float* __restrict__ SUM) {
  const int n = blockIdx.x;
  const int cnt = counts[n];
  if (cnt <= 0) return;                    // SUM[n] never read when count==0
  const int rs = row_start[n];

  __shared__ __align__(16) unsigned short Xh[64*XS_PAD];
  __shared__ int srcl[64];
  __shared__ float evl[192];
  const int t = threadIdx.x, lane = t & 63, wave = t >> 6;
  const int quad = lane >> 4, lcol = lane & 15;
  const int c0 = (t & 31) * 4, rbase = t >> 5;

  // prefetch first tile's records — one coalesced float4 per edge
  float4 ed = make_float4(0.f,0.f,0.f,0.f);
  if (t < 64 && t < cnt) ed = edata[rs + t];

  bf16x8 BW2[2][4];
  load_bfrags(W2t, wave, lane, BW2);
  float4 base = *(const float4*)(A2 + (size_t)n*128 + c0);   // g2b1 pre-folded
  float4 w0 = *(const float4*)(g2W1full + 256*128 + c0);
  float4 w1 = *(const float4*)(g2W1full + 257*128 + c0);
  float4 w2 = *(const float4*)(g2W1full + 258*128 + c0);
  const int colA = wave*32 + lcol, colB = colA + 16;
  const float b2A = b2[colA], b2B = b2[colB];
  float psA = 0.f, psB = 0.f;

  for (int t0 = 0; t0 < cnt; t0 += 64) {
    if (t0) __syncthreads();               // prev tile fully consumed
    if (t < 64) {
      srcl[t] = __float_as_int(ed.x);
      evl[3*t] = ed.y; evl[3*t+1] = ed.z; evl[3*t+2] = ed.w;
      int idx = t0 + 64 + t;               // prefetch next tile
      ed = make_float4(0.f,0.f,0.f,0.f);
      if (idx < cnt) ed = edata[rs + idx];
    }
    __syncthreads();
    // hoist meta-psum gathers: depend only on srcl, hidden under h+MFMA
    float mvA[16], mvB[16];
    #pragma unroll
    for (int rg = 0; rg < 4; ++rg)
      #pragma unroll
      for (int reg = 0; reg < 4; ++reg) {
        int k = rg*4 + reg, rl = rg*16 + quad*4 + reg;
        int s = srcl[rl];                  // s==0 for pad rows: loads valid
        mvA[k] = meta[(size_t)s*128 + colA];
        mvB[k] = meta[(size_t)s*128 + colB];
      }
    #pragma unroll
    for (int i = 0; i < 8; ++i) {          // h = relu(base + M2[src] + evec.Wc)
      int row = rbase + 8*i;
      float4 h = make_float4(0.f,0.f,0.f,0.f);
      if (t0 + row < cnt) {
        int s = srcl[row];
        float4 m = *(const float4*)(M2 + (size_t)s*128 + c0);
        float e0 = evl[3*row], e1 = evl[3*row+1], e2 = evl[3*row+2];
        h.x = fmaxf(base.x + m.x + e0*w0.x + e1*w1.x + e2*w2.x, 0.f);
        h.y = fmaxf(base.y + m.y + e0*w0.y + e1*w1.y + e2*w2.y, 0.f);
        h.z = fmaxf(base.z + m.z + e0*w0.z + e1*w1.z + e2*w2.z, 0.f);
        h.w = fmaxf(base.w + m.w + e0*w0.w + e1*w1.w + e2*w2.w, 0.f);
      }
      *(uint2*)(Xh + row*XS_PAD + c0) = make_uint2(pack2(h.x,h.y), pack2(h.z,h.w));
    }
    __syncthreads();
    f32x4 acc[4][2]; zero_acc(acc);
    mfma_layer(Xh, BW2, lane, acc);        // g = h @ g2W2
    #pragma unroll
    for (int rg = 0; rg < 4; ++rg)         // psum += (g+b2)*meta[src] (prefetched)
      #pragma unroll
      for (int reg = 0; reg < 4; ++reg) {
        int k = rg*4 + reg, rl = rg*16 + quad*4 + reg;
        if (t0 + rl < cnt) {
          psA += (acc[rg][0][reg] + b2A) * mvA[k];
          psB += (acc[rg][1][reg] + b2B) * mvB[k];
        }
      }
  }
  psA += __shfl_xor(psA, 16, 64); psA += __shfl_xor(psA, 32, 64);
  psB += __shfl_xor(psB, 16, 64); psB += __shfl_xor(psB, 32, 64);
  if (quad == 0) {                         // block owns node n: plain store
    SUM[(size_t)n*128 + colA] = psA;
    SUM[(size_t)n*128 + colB] = psB;
  }
}

// ------- fused node: double-buffered LDS, 4 barriers, hoisted gathers -------
__global__ __launch_bounds__(256) void fused_node(
    const float* __restrict__ res, const float* __restrict__ meta,
    const int* __restrict__ sec_ids, const float* __restrict__ pe,
    const float* __restrict__ g1W1full, const float* __restrict__ M1,
    const unsigned short* __restrict__ g1At,
    const unsigned short* __restrict__ g1W2t, const float* __restrict__ g1b1,
    const float* __restrict__ g1b2,
    const unsigned short* __restrict__ fW1t, const float* __restrict__ fb1v,
    const unsigned short* __restrict__ fW2t, const float* __restrict__ fb2v,
    const float* __restrict__ SUM, const int* __restrict__ counts, int msize,
    float* __restrict__ out, int rows) {
  __shared__ __align__(16) unsigned short Xa[64*XS_PAD];
  __shared__ __align__(16) unsigned short Xb[64*XS_PAD];
  __shared__ int   sids[64];
  __shared__ float pel[192];
  __shared__ float inv[64];
  const int t = threadIdx.x, lane = t & 63, wave = t >> 6;
  const int quad = lane >> 4, lcol = lane & 15;
  const int tile0 = blockIdx.x * 64;
  const int c0 = (t & 31) * 4, rbase = t >> 5;
  const int colA = wave*32 + lcol, colB = colA + 16;

  if (t < 64) {
    int gr = tile0 + t;
    sids[t] = (gr < rows) ? sec_ids[gr] : 0;
    float p0=0.f,p1=0.f,p2=0.f;
    if (gr < rows){ p0=pe[(size_t)gr*3]; p1=pe[(size_t)gr*3+1]; p2=pe[(size_t)gr*3+2]; }
    pel[3*t]=p0; pel[3*t+1]=p1; pel[3*t+2]=p2;
    int c = (gr < rows && gr < msize) ? counts[gr] : 0;
    inv[t] = (c > 0) ? 1.f/(float)c : 0.f;
  }
  bf16x8 BF[2][4];
  load_bfrags(g1At, wave, lane, BF);
  #pragma unroll
  for (int i = 0; i < 8; ++i) {                           // stage res -> Xa
    int row = rbase + 8*i, gr = tile0 + row;
    float4 v = make_float4(0.f,0.f,0.f,0.f);
    if (gr < rows) v = *(const float4*)(res + (size_t)gr*128 + c0);
    *(uint2*)(Xa + row*XS_PAD + c0) = make_uint2(pack2(v.x,v.y), pack2(v.z,v.w));
  }
  __syncthreads();                                        // B1: Xa + sids ready

  // hoist M1 gathers (need sids only) — consumed by h1 epilogue, hide under MFMA1
  float m1A[16], m1B[16];
  #pragma unroll
  for (int rg = 0; rg < 4; ++rg)
    #pragma unroll
    for (int reg = 0; reg < 4; ++reg) {
      int k = rg*4 + reg, row = rg*16 + quad*4 + reg;
      int sid = sids[row];
      m1A[k] = M1[(size_t)sid*128 + colA];
      m1B[k] = M1[(size_t)sid*128 + colB];
    }
  f32x4 acc[4][2]; zero_acc(acc);
  mfma_layer(Xa, BF, lane, acc);                          // res @ g1A
  load_bfrags(g1W2t, wave, lane, BF);
  {
    // h1 = relu(acc + M1[sec] + b1 - pe.Wc)  -> Xb  (no barrier: other buffer)
    const float b1A = g1b1[colA], b1B = g1b1[colB];
    const float wA0 = g1W1full[256*128+colA], wA1 = g1W1full[257*128+colA],
                wA2 = g1W1full[258*128+colA];
    const float wB0 = g1W1full[256*128+colB], wB1 = g1W1full[257*128+colB],
                wB2 = g1W1full[258*128+colB];
    #pragma unroll
    for (int rg = 0; rg < 4; ++rg)
      #pragma unroll
      for (int reg = 0; reg < 4; ++reg) {
        int k = rg*4 + reg, row = rg*16 + quad*4 + reg;
        float p0 = pel[3*row], p1 = pel[3*row+1], p2 = pel[3*row+2];
        float vA = acc[rg][0][reg] + m1A[k] + b1A - p0*wA0 - p1*wA1 - p2*wA2;
        float vB = acc[rg][1][reg] + m1B[k] + b1B - p0*wB0 - p1*wB1 - p2*wB2;
        Xb[row*XS_PAD + colA] = f2bf(fmaxf(vA, 0.f));
        Xb[row*XS_PAD + colB] = f2bf(fmaxf(vB, 0.f));
      }
  }
  __syncthreads();                                        // B2: h1 in Xb ready

  // hoist SUM gathers (HBM-cold): guarded by inv>0, hide under MFMA2
  float sAv[16], sBv[16];
  #pragma unroll
  for (int rg = 0; rg < 4; ++rg)
    #pragma unroll
    for (int reg = 0; reg < 4; ++reg) {
      int k = rg*4 + reg, row = rg*16 + quad*4 + reg, gr = tile0 + row;
      float iv = inv[row];
      sAv[k] = (iv > 0.f) ? SUM[(size_t)gr*128 + colA] : 0.f;
      sBv[k] = (iv > 0.f) ? SUM[(size_t)gr*128 + colB] : 0.f;
    }
  zero_acc(acc);
  mfma_layer(Xb, BF, lane, acc);                          // g = h1 @ g1W2
  load_bfrags(fW1t, wave, lane, BF);
  {
    // fused = res + (g+b2)*meta[sec] + SUM/cnt  -> Xa
    const float b2A = g1b2[colA], b2B = g1b2[colB];
    #pragma unroll
    for (int rg = 0; rg < 4; ++rg)
      #pragma unroll
      for (int reg = 0; reg < 4; ++reg) {
        int k = rg*4 + reg, row = rg*16 + quad*4 + reg, gr = tile0 + row;
        unsigned short oA = 0, oB = 0;
        if (gr < rows) {
          int sid = sids[row];
          float iv = inv[row];
          float gA = acc[rg][0][reg] + b2A, gB = acc[rg][1][reg] + b2B;
          float mA = meta[(size_t)sid*128 + colA], mB = meta[(size_t)sid*128 + colB];
          float rA = res[(size_t)gr*128 + colA],  rB = res[(size_t)gr*128 + colB];
          oA = f2bf(rA + gA*mA + sAv[k]*iv);
          oB = f2bf(rB + gB*mB + sBv[k]*iv);
        }
        Xa[row*XS_PAD + colA] = oA;
        Xa[row*XS_PAD + colB] = oB;
      }
  }
  __syncthreads();                                        // B3: fused in Xa ready
  zero_acc(acc);
  mfma_layer(Xa, BF, lane, acc);                          // fused @ fW1
  load_bfrags(fW2t, wave, lane, BF);
  {
    const float fb1A = fb1v[colA], fb1B = fb1v[colB];
    #pragma unroll
    for (int rg = 0; rg < 4; ++rg)                        // h2 -> Xb
      #pragma unroll
      for (int reg = 0; reg < 4; ++reg) {
        int row = rg*16 + quad*4 + reg;
        Xb[row*XS_PAD + colA] = f2bf(fmaxf(acc[rg][0][reg] + fb1A, 0.f));
        Xb[row*XS_PAD + colB] = f2bf(fmaxf(acc[rg][1][reg] + fb1B, 0.f));
      }
  }
  __syncthreads();                                        // B4: h2 in Xb ready
  zero_acc(acc);
  mfma_layer(Xb, BF, lane, acc);                          // out = h2 @ fW2
  {
    const float fb2A = fb2v[colA], fb2B = fb2v[colB];
    #pragma unroll
    for (int rg = 0; rg < 4; ++rg)                        // direct C-layout store
      #pragma unroll
      for (int reg = 0; reg < 4; ++reg) {
        int gr = tile0 + rg*16 + quad*4 + reg;
        if (gr < rows) {
          out[(size_t)gr*128 + colA] = acc[rg][0][reg] + fb2A;
          out[(size_t)gr*128 + colB] = acc[rg][1][reg] + fb2B;
        }
      }
  }
}

extern "C" void kernel_launch(void* const* d_in, const int* in_sizes, int n_in,
                              void* d_out, int out_size, void* d_ws, size_t ws_size,
                              hipStream_t stream) {
  const float* res     = (const float*)d_in[0];
  const float* meta    = (const float*)d_in[1];
  const int*   sec_ids = (const int*)  d_in[2];
  const float* pe      = (const float*)d_in[3];
  const int*   edge    = (const int*)  d_in[4];
  const float* evec    = (const float*)d_in[5];
  const float* g1W1 = (const float*)d_in[6];
  const float* g1b1 = (const float*)d_in[7];
  const float* g1W2 = (const float*)d_in[8];
  const float* g1b2 = (const float*)d_in[9];
  const float* g2W1 = (const float*)d_in[10];
  const float* g2b1 = (const float*)d_in[11];
  const float* g2W2 = (const float*)d_in[12];
  const float* g2b2 = (const float*)d_in[13];
  const float* fW1  = (const float*)d_in[14];
  const float* fb1  = (const float*)d_in[15];
  const float* fW2  = (const float*)d_in[16];
  const float* fb2  = (const float*)d_in[17];

  const int N = in_sizes[0] / 128;
  const int M = in_sizes[1] / 128;
  const int E = in_sizes[4] / 2;
  const int* src = edge;
  const int* dst = edge + E;

  float* ws = (float*)d_ws;
  float* A2   = ws;                          // M*128
  float* M2   = A2 + (size_t)M*128;          // M*128
  float* M1   = M2 + (size_t)M*128;          // M*128 (meta @ g1B, f32)
  float* SUMb = M1 + (size_t)M*128;          // M*128 (read only when count>0)
  int* counts     = (int*)(SUMb + (size_t)M*128);
  int* row_startp = counts + M;
  int* cursor     = row_startp + M;
  uintptr_t ap = (uintptr_t)(cursor + M);
  ap = (ap + 15) & ~(uintptr_t)15;
  float4* edata = (float4*)ap;               // E x 16B packed records
  uintptr_t wp = (uintptr_t)(edata + E);
  wp = (wp + 15) & ~(uintptr_t)15;
  unsigned short* Wt = (unsigned short*)wp;  // 8 slabs x 16384
  unsigned short* W_g1A  = Wt + 0*16384;
  unsigned short* W_g1B  = Wt + 1*16384;
  unsigned short* W_g1W2 = Wt + 2*16384;
  unsigned short* W_g2A  = Wt + 3*16384;
  unsigned short* W_g2B  = Wt + 4*16384;
  unsigned short* W_g2W2 = Wt + 5*16384;
  unsigned short* W_fW1  = Wt + 6*16384;
  unsigned short* W_fW2  = Wt + 7*16384;
  float* out = (float*)d_out;

  WPtrs p;
  p.s[0] = g1W1;            p.s[1] = g1W1 + 128*128;  p.s[2] = g1W2;
  p.s[3] = g2W1;            p.s[4] = g2W1 + 128*128;  p.s[5] = g2W2;
  p.s[6] = fW1;             p.s[7] = fW2;

  const int nbMt   = (M + 63) / 64;
  const int nbN    = (N + 63) / 64;
  const int nbE    = (E + 255) / 256;
  const int nbPrep = 3*nbMt;                 // A2, M2, M1 slabs

  // 1: W transposes + zero counts
  transpose_w8<<<128, 256, 0, stream>>>(p, Wt, counts, M);
  // 2: A2/M2/M1 prep + histogram
  prep_and_hist<<<nbPrep + nbE, 256, 0, stream>>>(res, meta, W_g2A, W_g2B, W_g1B,
                                                  g2b1, A2, M2, M1, M, nbPrep,
                                                  dst, counts, E);
  // 3: scan (single block)
  scan_all<<<1, 1024, 0, stream>>>(counts, row_startp, cursor, M);
  // 4: packed CSR edge records
  fill_kernel<<<nbE, 256, 0, stream>>>(dst, src, evec, cursor, edata, E);
  // 5: edge phase — one block per node, no atomics
  edge_mfma<<<M, 256, 0, stream>>>(A2, M2, meta, edata, row_startp, counts,
                                   g2W1, W_g2W2, g2b2, SUMb);
  // 6: fused node path (double-buffered, 4 barriers)
  fused_node<<<nbN, 256, 0, stream>>>(res, meta, sec_ids, pe, g1W1, M1,
                                      W_g1A, W_g1W2, g1b1, g1b2,
                                      W_fW1, fb1, W_fW2, fb2,
                                      SUMb, counts, M, out, N);
}

// Round 7
// 368.107 us; speedup vs baseline: 1.2522x; 1.0276x over previous
//
#include <hip/hip_runtime.h>

// GatedMetaFusion R11 = R8 fused_node (81us, verified best) + R10 edge hoist (−25us).
//   transpose_w8: W^T bf16 x8 + zero counts
//   prep_and_hist: A2 = res[0:M]@g2A + g2b1, M2 = meta@g2B, M1 = meta@g1B, + hist
//   scan_all: single-block scan
//   fill: packed 16B edge records {src, evec0..2} in CSR order
//   edge (grid = M): meta-psum gathers hoisted BEFORE the MFMA (verified win)
//   fused_node: SINGLE LDS buffer, 7 barriers, 68 VGPR (dbuf variant was 108us —
//     LDS 36KB halved residency; reverted).
//
// MFMA 16x16x32 bf16 layouts (verified): A[m=lane&15][k=quad*8+j],
// B from W^T row-major 16B/lane, C/D: col=lane&15, row=quad*4+reg.

typedef short bf16x8 __attribute__((ext_vector_type(8)));
typedef float f32x4  __attribute__((ext_vector_type(4)));

#define XS_PAD 136   // bf16 row stride (272B, 16B-aligned)

__device__ __forceinline__ unsigned short f2bf(float f){
  union { float f; unsigned u; } v; v.f = f;
  return (unsigned short)((v.u + 0x7FFFu + ((v.u >> 16) & 1u)) >> 16);
}
__device__ __forceinline__ unsigned pack2(float a, float b){
  return (unsigned)f2bf(a) | ((unsigned)f2bf(b) << 16);
}

__device__ __forceinline__ void mfma_layer(const unsigned short* Xs,
                                           const bf16x8 (&B)[2][4],
                                           int lane, f32x4 (&acc)[4][2]) {
  const int lcol = lane & 15, quad = lane >> 4;
  #pragma unroll
  for (int rg = 0; rg < 4; ++rg) {
    bf16x8 A[4];
    const unsigned short* ab = Xs + (rg*16 + lcol)*XS_PAD + quad*8;
    #pragma unroll
    for (int kk = 0; kk < 4; ++kk) A[kk] = *(const bf16x8*)(ab + kk*32);
    #pragma unroll
    for (int ctl = 0; ctl < 2; ++ctl)
      #pragma unroll
      for (int kk = 0; kk < 4; ++kk)
        acc[rg][ctl] = __builtin_amdgcn_mfma_f32_16x16x32_bf16(
            A[kk], B[ctl][kk], acc[rg][ctl], 0, 0, 0);
  }
}

__device__ __forceinline__ void load_bfrags(const unsigned short* __restrict__ Wt,
                                            int wave, int lane, bf16x8 (&B)[2][4]) {
  const int lcol = lane & 15, quad = lane >> 4;
  #pragma unroll
  for (int ctl = 0; ctl < 2; ++ctl) {
    int col = (wave*2 + ctl)*16 + lcol;
    #pragma unroll
    for (int kk = 0; kk < 4; ++kk)
      B[ctl][kk] = *(const bf16x8*)(Wt + (size_t)col*128 + kk*32 + quad*8);
  }
}

__device__ __forceinline__ void zero_acc(f32x4 (&acc)[4][2]) {
  #pragma unroll
  for (int rg = 0; rg < 4; ++rg)
    #pragma unroll
    for (int ctl = 0; ctl < 2; ++ctl) {
      acc[rg][ctl][0]=0.f; acc[rg][ctl][1]=0.f;
      acc[rg][ctl][2]=0.f; acc[rg][ctl][3]=0.f;
    }
}

// ---------------- 8-slab W^T bf16 prep + zero counts ----------------
struct WPtrs { const float* s[8]; };
__global__ __launch_bounds__(256) void transpose_w8(WPtrs p,
                                                    unsigned short* __restrict__ dstbase,
                                                    int* __restrict__ counts, int M) {
  int slab = blockIdx.x >> 4, blk = blockIdx.x & 15;
  const float* W = p.s[slab];
  unsigned short* Wt = dstbase + (size_t)slab*16384;
  int c  = blk*8 + (threadIdx.x >> 5);
  int k0 = (threadIdx.x & 31) * 4;
  unsigned short o[4];
  #pragma unroll
  for (int j = 0; j < 4; ++j) o[j] = f2bf(W[(size_t)(k0 + j)*128 + c]);
  *(uint2*)(Wt + (size_t)c*128 + k0) =
      make_uint2((unsigned)o[0] | ((unsigned)o[1] << 16),
                 (unsigned)o[2] | ((unsigned)o[3] << 16));
  int tid = blockIdx.x*256 + threadIdx.x;
  int tot = gridDim.x*256;
  for (int i = tid; i < M; i += tot) counts[i] = 0;
}

// --- prep (A2 = res[0:M]@g2A + b1, M2 = meta@g2B, M1 = meta@g1B) + hist blocks ---
__global__ __launch_bounds__(256) void prep_and_hist(
    const float* __restrict__ res, const float* __restrict__ meta,
    const unsigned short* __restrict__ WAt, const unsigned short* __restrict__ WBt,
    const unsigned short* __restrict__ WCt, const float* __restrict__ b1,
    float* __restrict__ A2, float* __restrict__ M2, float* __restrict__ M1,
    int mrows, int nbPrep,
    const int* __restrict__ dst, int* __restrict__ counts, int E) {
  if ((int)blockIdx.x >= nbPrep) {              // histogram portion of the grid
    int e = ((int)blockIdx.x - nbPrep)*256 + threadIdx.x;
    if (e < E) atomicAdd(&counts[dst[e]], 1);
    return;
  }
  __shared__ __align__(16) unsigned short Xs[64*XS_PAD];
  const int t = threadIdx.x, lane = t & 63, wave = t >> 6;
  const int quad = lane >> 4, lcol = lane & 15;
  const int third = nbPrep / 3;
  const int yy = (int)blockIdx.x / third;
  const int bx = (int)blockIdx.x - yy*third;
  const int tile0 = bx * 64;
  const float* X = (yy == 0) ? res : meta;
  const unsigned short* Wt = (yy == 0) ? WAt : (yy == 1) ? WBt : WCt;
  float* Y = (yy == 0) ? A2 : (yy == 1) ? M2 : M1;
  bf16x8 B[2][4];
  load_bfrags(Wt, wave, lane, B);
  #pragma unroll
  for (int i = 0; i < 8; ++i) {
    int f = t + i*256, row = f >> 5, c4 = f & 31;
    int gr = tile0 + row;
    float4 v = make_float4(0.f,0.f,0.f,0.f);
    if (gr < mrows) v = *(const float4*)(X + (size_t)gr*128 + c4*4);
    *(uint2*)(Xs + row*XS_PAD + c4*4) = make_uint2(pack2(v.x,v.y), pack2(v.z,v.w));
  }
  __syncthreads();
  f32x4 acc[4][2]; zero_acc(acc);
  mfma_layer(Xs, B, lane, acc);
  #pragma unroll
  for (int rg = 0; rg < 4; ++rg)
    #pragma unroll
    for (int ctl = 0; ctl < 2; ++ctl) {
      int col = (wave*2 + ctl)*16 + lcol;
      float badd = 0.f;
      if (yy == 0) badd = b1[col];              // fold g2b1 into A2
      #pragma unroll
      for (int reg = 0; reg < 4; ++reg) {
        int gr = tile0 + rg*16 + quad*4 + reg;
        if (gr < mrows) Y[(size_t)gr*128 + col] = acc[rg][ctl][reg] + badd;
      }
    }
}

// ---------------- single-block scan (chunked, M<=2048 per chunk) ----------------
__global__ __launch_bounds__(1024) void scan_all(const int* __restrict__ counts,
                                                 int* __restrict__ row_start,
                                                 int* __restrict__ cursor, int M) {
  __shared__ int s[1024];
  __shared__ int carry_s;
  const int t = threadIdx.x;
  if (t == 0) carry_s = 0;
  __syncthreads();
  for (int base = 0; base < M; base += 2048) {
    int i0 = base + 2*t, i1 = i0 + 1;
    int c0 = (i0 < M) ? counts[i0] : 0;
    int c1 = (i1 < M) ? counts[i1] : 0;
    int pair = c0 + c1;
    s[t] = pair; __syncthreads();
    for (int off = 1; off < 1024; off <<= 1) {
      int x = (t >= off) ? s[t-off] : 0; __syncthreads();
      s[t] += x; __syncthreads();
    }
    int carry = carry_s;
    int excl = carry + s[t] - pair;
    if (i0 < M) { row_start[i0] = excl;       cursor[i0] = excl; }
    if (i1 < M) { row_start[i1] = excl + c0;  cursor[i1] = excl + c0; }
    __syncthreads();
    if (t == 1023) carry_s = carry + s[1023];
    __syncthreads();
  }
}

// -------- fill: packed 16B records {src, evec0..2} in CSR order --------
__global__ void fill_kernel(const int* __restrict__ dst, const int* __restrict__ src,
                            const float* __restrict__ evec, int* __restrict__ cursor,
                            float4* __restrict__ edata, int E) {
  int e = blockIdx.x*256 + threadIdx.x;
  if (e < E) {
    int p = atomicAdd(&cursor[dst[e]], 1);
    edata[p] = make_float4(__int_as_float(src[e]),
                           evec[(size_t)e*3], evec[(size_t)e*3+1], evec[(size_t)e*3+2]);
  }
}

// ---------------- edge phase: grid = M, one block per node ----------------
__global__ __launch_bounds__(256) void edge_mfma(
    const float* __restrict__ A2, const float* __restrict__ M2,
    const float* __restrict__ meta, const float4* __restrict__ edata,
    const int* __restrict__ row_start, const int* __restrict__ counts,
    const float* __restrict__ g2W1full,
    const unsigned short* __restrict__ W2t, const float* __restrict__ b2,
    float* __restrict__ SUM) {
  const int n = blockIdx.x;
  const int cnt = counts[n];
  if (cnt <= 0) return;                    // SUM[n] never read when count==0
  const int rs = row_start[n];

  __shared__ __align__(16) unsigned short Xh[64*XS_PAD];
  __shared__ int srcl[64];
  __shared__ float evl[192];
  const int t = threadIdx.x, lane = t & 63, wave = t >> 6;
  const int quad = lane >> 4, lcol = lane & 15;
  const int c0 = (t & 31) * 4, rbase = t >> 5;

  // prefetch first tile's records — one coalesced float4 per edge
  float4 ed = make_float4(0.f,0.f,0.f,0.f);
  if (t < 64 && t < cnt) ed = edata[rs + t];

  bf16x8 BW2[2][4];
  load_bfrags(W2t, wave, lane, BW2);
  float4 base = *(const float4*)(A2 + (size_t)n*128 + c0);   // g2b1 pre-folded
  float4 w0 = *(const float4*)(g2W1full + 256*128 + c0);
  float4 w1 = *(const float4*)(g2W1full + 257*128 + c0);
  float4 w2 = *(const float4*)(g2W1full + 258*128 + c0);
  const int colA = wave*32 + lcol, colB = colA + 16;
  const float b2A = b2[colA], b2B = b2[colB];
  float psA = 0.f, psB = 0.f;

  for (int t0 = 0; t0 < cnt; t0 += 64) {
    if (t0) __syncthreads();               // prev tile fully consumed
    if (t < 64) {
      srcl[t] = __float_as_int(ed.x);
      evl[3*t] = ed.y; evl[3*t+1] = ed.z; evl[3*t+2] = ed.w;
      int idx = t0 + 64 + t;               // prefetch next tile
      ed = make_float4(0.f,0.f,0.f,0.f);
      if (idx < cnt) ed = edata[rs + idx];
    }
    __syncthreads();
    // hoist meta-psum gathers: depend only on srcl, hidden under h+MFMA
    float mvA[16], mvB[16];
    #pragma unroll
    for (int rg = 0; rg < 4; ++rg)
      #pragma unroll
      for (int reg = 0; reg < 4; ++reg) {
        int k = rg*4 + reg, rl = rg*16 + quad*4 + reg;
        int s = srcl[rl];                  // s==0 for pad rows: loads valid
        mvA[k] = meta[(size_t)s*128 + colA];
        mvB[k] = meta[(size_t)s*128 + colB];
      }
    #pragma unroll
    for (int i = 0; i < 8; ++i) {          // h = relu(base + M2[src] + evec.Wc)
      int row = rbase + 8*i;
      float4 h = make_float4(0.f,0.f,0.f,0.f);
      if (t0 + row < cnt) {
        int s = srcl[row];
        float4 m = *(const float4*)(M2 + (size_t)s*128 + c0);
        float e0 = evl[3*row], e1 = evl[3*row+1], e2 = evl[3*row+2];
        h.x = fmaxf(base.x + m.x + e0*w0.x + e1*w1.x + e2*w2.x, 0.f);
        h.y = fmaxf(base.y + m.y + e0*w0.y + e1*w1.y + e2*w2.y, 0.f);
        h.z = fmaxf(base.z + m.z + e0*w0.z + e1*w1.z + e2*w2.z, 0.f);
        h.w = fmaxf(base.w + m.w + e0*w0.w + e1*w1.w + e2*w2.w, 0.f);
      }
      *(uint2*)(Xh + row*XS_PAD + c0) = make_uint2(pack2(h.x,h.y), pack2(h.z,h.w));
    }
    __syncthreads();
    f32x4 acc[4][2]; zero_acc(acc);
    mfma_layer(Xh, BW2, lane, acc);        // g = h @ g2W2
    #pragma unroll
    for (int rg = 0; rg < 4; ++rg)         // psum += (g+b2)*meta[src] (prefetched)
      #pragma unroll
      for (int reg = 0; reg < 4; ++reg) {
        int k = rg*4 + reg, rl = rg*16 + quad*4 + reg;
        if (t0 + rl < cnt) {
          psA += (acc[rg][0][reg] + b2A) * mvA[k];
          psB += (acc[rg][1][reg] + b2B) * mvB[k];
        }
      }
  }
  psA += __shfl_xor(psA, 16, 64); psA += __shfl_xor(psA, 32, 64);
  psB += __shfl_xor(psB, 16, 64); psB += __shfl_xor(psB, 32, 64);
  if (quad == 0) {                         // block owns node n: plain store
    SUM[(size_t)n*128 + colA] = psA;
    SUM[(size_t)n*128 + colB] = psB;
  }
}

// ------- fused node path: R8 version (single buffer, 7 barriers, 68 VGPR) -------
__global__ __launch_bounds__(256) void fused_node(
    const float* __restrict__ res, const float* __restrict__ meta,
    const int* __restrict__ sec_ids, const float* __restrict__ pe,
    const float* __restrict__ g1W1full, const float* __restrict__ M1,
    const unsigned short* __restrict__ g1At,
    const unsigned short* __restrict__ g1W2t, const float* __restrict__ g1b1,
    const float* __restrict__ g1b2,
    const unsigned short* __restrict__ fW1t, const float* __restrict__ fb1v,
    const unsigned short* __restrict__ fW2t, const float* __restrict__ fb2v,
    const float* __restrict__ SUM, const int* __restrict__ counts, int msize,
    float* __restrict__ out, int rows) {
  __shared__ __align__(16) unsigned short Xs[64*XS_PAD];
  __shared__ int   sids[64];
  __shared__ float pel[192];
  __shared__ float inv[64];
  const int t = threadIdx.x, lane = t & 63, wave = t >> 6;
  const int quad = lane >> 4, lcol = lane & 15;
  const int tile0 = blockIdx.x * 64;
  const int c0 = (t & 31) * 4, rbase = t >> 5;
  const int colA = wave*32 + lcol, colB = colA + 16;

  if (t < 64) {
    int gr = tile0 + t;
    sids[t] = (gr < rows) ? sec_ids[gr] : 0;
    float p0=0.f,p1=0.f,p2=0.f;
    if (gr < rows){ p0=pe[(size_t)gr*3]; p1=pe[(size_t)gr*3+1]; p2=pe[(size_t)gr*3+2]; }
    pel[3*t]=p0; pel[3*t+1]=p1; pel[3*t+2]=p2;
    int c = (gr < rows && gr < msize) ? counts[gr] : 0;
    inv[t] = (c > 0) ? 1.f/(float)c : 0.f;
  }
  bf16x8 BF[2][4];
  load_bfrags(g1At, wave, lane, BF);
  #pragma unroll
  for (int i = 0; i < 8; ++i) {                           // stage res
    int row = rbase + 8*i, gr = tile0 + row;
    float4 v = make_float4(0.f,0.f,0.f,0.f);
    if (gr < rows) v = *(const float4*)(res + (size_t)gr*128 + c0);
    *(uint2*)(Xs + row*XS_PAD + c0) = make_uint2(pack2(v.x,v.y), pack2(v.z,v.w));
  }
  __syncthreads();                                        // 1: Xs(res) + sids
  f32x4 acc[4][2]; zero_acc(acc);
  mfma_layer(Xs, BF, lane, acc);                          // res @ g1A
  load_bfrags(g1W2t, wave, lane, BF);
  __syncthreads();                                        // 2: Xs consumed
  {
    // h1 = relu(acc + M1[sec] + b1 - pe.Wc) straight in C-layout (no MFMA stage)
    const float b1A = g1b1[colA], b1B = g1b1[colB];
    const float wA0 = g1W1full[256*128+colA], wA1 = g1W1full[257*128+colA],
                wA2 = g1W1full[258*128+colA];
    const float wB0 = g1W1full[256*128+colB], wB1 = g1W1full[257*128+colB],
                wB2 = g1W1full[258*128+colB];
    #pragma unroll
    for (int rg = 0; rg < 4; ++rg)
      #pragma unroll
      for (int reg = 0; reg < 4; ++reg) {
        int row = rg*16 + quad*4 + reg;
        int sid = sids[row];
        float m1A = M1[(size_t)sid*128 + colA];
        float m1B = M1[(size_t)sid*128 + colB];
        float p0 = pel[3*row], p1 = pel[3*row+1], p2 = pel[3*row+2];
        float vA = acc[rg][0][reg] + m1A + b1A - p0*wA0 - p1*wA1 - p2*wA2;
        float vB = acc[rg][1][reg] + m1B + b1B - p0*wB0 - p1*wB1 - p2*wB2;
        Xs[row*XS_PAD + colA] = f2bf(fmaxf(vA, 0.f));
        Xs[row*XS_PAD + colB] = f2bf(fmaxf(vB, 0.f));
      }
  }
  __syncthreads();                                        // 3: h1 staged
  zero_acc(acc);
  mfma_layer(Xs, BF, lane, acc);                          // g = h1 @ g1W2
  load_bfrags(fW1t, wave, lane, BF);
  __syncthreads();                                        // 4: Xs consumed
  {
    const float b2A = g1b2[colA], b2B = g1b2[colB];
    #pragma unroll
    for (int rg = 0; rg < 4; ++rg)     // fuse in C-layout straight from acc
      #pragma unroll
      for (int reg = 0; reg < 4; ++reg) {
        int row = rg*16 + quad*4 + reg, gr = tile0 + row;
        unsigned short oA = 0, oB = 0;
        if (gr < rows) {
          int sid = sids[row];
          float gA = acc[rg][0][reg] + b2A, gB = acc[rg][1][reg] + b2B;
          float mA = meta[(size_t)sid*128 + colA], mB = meta[(size_t)sid*128 + colB];
          float rA = res[(size_t)gr*128 + colA],  rB = res[(size_t)gr*128 + colB];
          float iv = inv[row];
          float sA = 0.f, sB = 0.f;
          if (iv > 0.f) {
            sA = SUM[(size_t)gr*128 + colA] * iv;
            sB = SUM[(size_t)gr*128 + colB] * iv;
          }
          oA = f2bf(rA + gA*mA + sA);
          oB = f2bf(rB + gB*mB + sB);
        }
        Xs[row*XS_PAD + colA] = oA;
        Xs[row*XS_PAD + colB] = oB;
      }
  }
  __syncthreads();                                        // 5: fused staged
  zero_acc(acc);
  mfma_layer(Xs, BF, lane, acc);                          // fused @ fW1
  load_bfrags(fW2t, wave, lane, BF);
  __syncthreads();                                        // 6: Xs consumed
  {
    const float fb1A = fb1v[colA], fb1B = fb1v[colB];
    #pragma unroll
    for (int rg = 0; rg < 4; ++rg)                        // h2 -> Xs
      #pragma unroll
      for (int reg = 0; reg < 4; ++reg) {
        int row = rg*16 + quad*4 + reg;
        Xs[row*XS_PAD + colA] = f2bf(fmaxf(acc[rg][0][reg] + fb1A, 0.f));
        Xs[row*XS_PAD + colB] = f2bf(fmaxf(acc[rg][1][reg] + fb1B, 0.f));
      }
  }
  __syncthreads();                                        // 7: h2 staged
  zero_acc(acc);
  mfma_layer(Xs, BF, lane, acc);                          // out = h2 @ fW2
  {
    const float fb2A = fb2v[colA], fb2B = fb2v[colB];
    #pragma unroll
    for (int rg = 0; rg < 4; ++rg)                        // direct C-layout store
      #pragma unroll
      for (int reg = 0; reg < 4; ++reg) {
        int gr = tile0 + rg*16 + quad*4 + reg;
        if (gr < rows) {
          out[(size_t)gr*128 + colA] = acc[rg][0][reg] + fb2A;
          out[(size_t)gr*128 + colB] = acc[rg][1][reg] + fb2B;
        }
      }
  }
}

extern "C" void kernel_launch(void* const* d_in, const int* in_sizes, int n_in,
                              void* d_out, int out_size, void* d_ws, size_t ws_size,
                              hipStream_t stream) {
  const float* res     = (const float*)d_in[0];
  const float* meta    = (const float*)d_in[1];
  const int*   sec_ids = (const int*)  d_in[2];
  const float* pe      = (const float*)d_in[3];
  const int*   edge    = (const int*)  d_in[4];
  const float* evec    = (const float*)d_in[5];
  const float* g1W1 = (const float*)d_in[6];
  const float* g1b1 = (const float*)d_in[7];
  const float* g1W2 = (const float*)d_in[8];
  const float* g1b2 = (const float*)d_in[9];
  const float* g2W1 = (const float*)d_in[10];
  const float* g2b1 = (const float*)d_in[11];
  const float* g2W2 = (const float*)d_in[12];
  const float* g2b2 = (const float*)d_in[13];
  const float* fW1  = (const float*)d_in[14];
  const float* fb1  = (const float*)d_in[15];
  const float* fW2  = (const float*)d_in[16];
  const float* fb2  = (const float*)d_in[17];

  const int N = in_sizes[0] / 128;
  const int M = in_sizes[1] / 128;
  const int E = in_sizes[4] / 2;
  const int* src = edge;
  const int* dst = edge + E;

  float* ws = (float*)d_ws;
  float* A2   = ws;                          // M*128
  float* M2   = A2 + (size_t)M*128;          // M*128
  float* M1   = M2 + (size_t)M*128;          // M*128 (meta @ g1B, f32)
  float* SUMb = M1 + (size_t)M*128;          // M*128 (read only when count>0)
  int* counts     = (int*)(SUMb + (size_t)M*128);
  int* row_startp = counts + M;
  int* cursor     = row_startp + M;
  uintptr_t ap = (uintptr_t)(cursor + M);
  ap = (ap + 15) & ~(uintptr_t)15;
  float4* edata = (float4*)ap;               // E x 16B packed records
  uintptr_t wp = (uintptr_t)(edata + E);
  wp = (wp + 15) & ~(uintptr_t)15;
  unsigned short* Wt = (unsigned short*)wp;  // 8 slabs x 16384
  unsigned short* W_g1A  = Wt + 0*16384;
  unsigned short* W_g1B  = Wt + 1*16384;
  unsigned short* W_g1W2 = Wt + 2*16384;
  unsigned short* W_g2A  = Wt + 3*16384;
  unsigned short* W_g2B  = Wt + 4*16384;
  unsigned short* W_g2W2 = Wt + 5*16384;
  unsigned short* W_fW1  = Wt + 6*16384;
  unsigned short* W_fW2  = Wt + 7*16384;
  float* out = (float*)d_out;

  WPtrs p;
  p.s[0] = g1W1;            p.s[1] = g1W1 + 128*128;  p.s[2] = g1W2;
  p.s[3] = g2W1;            p.s[4] = g2W1 + 128*128;  p.s[5] = g2W2;
  p.s[6] = fW1;             p.s[7] = fW2;

  const int nbMt   = (M + 63) / 64;
  const int nbN    = (N + 63) / 64;
  const int nbE    = (E + 255) / 256;
  const int nbPrep = 3*nbMt;                 // A2, M2, M1 slabs

  // 1: W transposes + zero counts
  transpose_w8<<<128, 256, 0, stream>>>(p, Wt, counts, M);
  // 2: A2/M2/M1 prep + histogram
  prep_and_hist<<<nbPrep + nbE, 256, 0, stream>>>(res, meta, W_g2A, W_g2B, W_g1B,
                                                  g2b1, A2, M2, M1, M, nbPrep,
                                                  dst, counts, E);
  // 3: scan (single block)
  scan_all<<<1, 1024, 0, stream>>>(counts, row_startp, cursor, M);
  // 4: packed CSR edge records
  fill_kernel<<<nbE, 256, 0, stream>>>(dst, src, evec, cursor, edata, E);
  // 5: edge phase — one block per node, no atomics
  edge_mfma<<<M, 256, 0, stream>>>(A2, M2, meta, edata, row_startp, counts,
                                   g2W1, W_g2W2, g2b2, SUMb);
  // 6: fused node path (single-buffer R8 version)
  fused_node<<<nbN, 256, 0, stream>>>(res, meta, sec_ids, pe, g1W1, M1,
                                      W_g1A, W_g1W2, g1b1, g1b2,
                                      W_fW1, fb1, W_fW2, fb2,
                                      SUMb, counts, M, out, N);
}

// Round 8
// 354.375 us; speedup vs baseline: 1.3008x; 1.0387x over previous
//
#include <hip/hip_runtime.h>

// GatedMetaFusion R12 = R11 + 2-tile fused_node.
//   transpose_w8: W^T bf16 x8 + zero counts
//   prep_and_hist: A2 = res[0:M]@g2A + g2b1, M2 = meta@g2B, M1 = meta@g1B, + hist
//   scan_all: single-block scan
//   fill: packed 16B edge records {src, evec0..2} in CSR order
//   edge (grid = M): meta-psum gathers hoisted BEFORE the MFMA (verified win)
//   fused_node2: TWO 64-row tiles per block (rows b*128..b*128+127).
//     Same 7-barrier structure, but each phase does tileA then tileB:
//     mfmaA;mfmaB (independent -> pipe overlap), epiA;epiB (2x gathers in flight).
//     Per-tile barriers halved; B-frag loads shared. 4 blocks/CU x 2 tiles
//     = 8 resident tiles/CU (same as R11's 8 blocks x 1 tile).
//
// MFMA 16x16x32 bf16 layouts (verified): A[m=lane&15][k=quad*8+j],
// B from W^T row-major 16B/lane, C/D: col=lane&15, row=quad*4+reg.

typedef short bf16x8 __attribute__((ext_vector_type(8)));
typedef float f32x4  __attribute__((ext_vector_type(4)));

#define XS_PAD 136   // bf16 row stride (272B, 16B-aligned)

__device__ __forceinline__ unsigned short f2bf(float f){
  union { float f; unsigned u; } v; v.f = f;
  return (unsigned short)((v.u + 0x7FFFu + ((v.u >> 16) & 1u)) >> 16);
}
__device__ __forceinline__ unsigned pack2(float a, float b){
  return (unsigned)f2bf(a) | ((unsigned)f2bf(b) << 16);
}

__device__ __forceinline__ void mfma_layer(const unsigned short* Xs,
                                           const bf16x8 (&B)[2][4],
                                           int lane, f32x4 (&acc)[4][2]) {
  const int lcol = lane & 15, quad = lane >> 4;
  #pragma unroll
  for (int rg = 0; rg < 4; ++rg) {
    bf16x8 A[4];
    const unsigned short* ab = Xs + (rg*16 + lcol)*XS_PAD + quad*8;
    #pragma unroll
    for (int kk = 0; kk < 4; ++kk) A[kk] = *(const bf16x8*)(ab + kk*32);
    #pragma unroll
    for (int ctl = 0; ctl < 2; ++ctl)
      #pragma unroll
      for (int kk = 0; kk < 4; ++kk)
        acc[rg][ctl] = __builtin_amdgcn_mfma_f32_16x16x32_bf16(
            A[kk], B[ctl][kk], acc[rg][ctl], 0, 0, 0);
  }
}

__device__ __forceinline__ void load_bfrags(const unsigned short* __restrict__ Wt,
                                            int wave, int lane, bf16x8 (&B)[2][4]) {
  const int lcol = lane & 15, quad = lane >> 4;
  #pragma unroll
  for (int ctl = 0; ctl < 2; ++ctl) {
    int col = (wave*2 + ctl)*16 + lcol;
    #pragma unroll
    for (int kk = 0; kk < 4; ++kk)
      B[ctl][kk] = *(const bf16x8*)(Wt + (size_t)col*128 + kk*32 + quad*8);
  }
}

__device__ __forceinline__ void zero_acc(f32x4 (&acc)[4][2]) {
  #pragma unroll
  for (int rg = 0; rg < 4; ++rg)
    #pragma unroll
    for (int ctl = 0; ctl < 2; ++ctl) {
      acc[rg][ctl][0]=0.f; acc[rg][ctl][1]=0.f;
      acc[rg][ctl][2]=0.f; acc[rg][ctl][3]=0.f;
    }
}

// ---------------- 8-slab W^T bf16 prep + zero counts ----------------
struct WPtrs { const float* s[8]; };
__global__ __launch_bounds__(256) void transpose_w8(WPtrs p,
                                                    unsigned short* __restrict__ dstbase,
                                                    int* __restrict__ counts, int M) {
  int slab = blockIdx.x >> 4, blk = blockIdx.x & 15;
  const float* W = p.s[slab];
  unsigned short* Wt = dstbase + (size_t)slab*16384;
  int c  = blk*8 + (threadIdx.x >> 5);
  int k0 = (threadIdx.x & 31) * 4;
  unsigned short o[4];
  #pragma unroll
  for (int j = 0; j < 4; ++j) o[j] = f2bf(W[(size_t)(k0 + j)*128 + c]);
  *(uint2*)(Wt + (size_t)c*128 + k0) =
      make_uint2((unsigned)o[0] | ((unsigned)o[1] << 16),
                 (unsigned)o[2] | ((unsigned)o[3] << 16));
  int tid = blockIdx.x*256 + threadIdx.x;
  int tot = gridDim.x*256;
  for (int i = tid; i < M; i += tot) counts[i] = 0;
}

// --- prep (A2 = res[0:M]@g2A + b1, M2 = meta@g2B, M1 = meta@g1B) + hist blocks ---
__global__ __launch_bounds__(256) void prep_and_hist(
    const float* __restrict__ res, const float* __restrict__ meta,
    const unsigned short* __restrict__ WAt, const unsigned short* __restrict__ WBt,
    const unsigned short* __restrict__ WCt, const float* __restrict__ b1,
    float* __restrict__ A2, float* __restrict__ M2, float* __restrict__ M1,
    int mrows, int nbPrep,
    const int* __restrict__ dst, int* __restrict__ counts, int E) {
  if ((int)blockIdx.x >= nbPrep) {              // histogram portion of the grid
    int e = ((int)blockIdx.x - nbPrep)*256 + threadIdx.x;
    if (e < E) atomicAdd(&counts[dst[e]], 1);
    return;
  }
  __shared__ __align__(16) unsigned short Xs[64*XS_PAD];
  const int t = threadIdx.x, lane = t & 63, wave = t >> 6;
  const int quad = lane >> 4, lcol = lane & 15;
  const int third = nbPrep / 3;
  const int yy = (int)blockIdx.x / third;
  const int bx = (int)blockIdx.x - yy*third;
  const int tile0 = bx * 64;
  const float* X = (yy == 0) ? res : meta;
  const unsigned short* Wt = (yy == 0) ? WAt : (yy == 1) ? WBt : WCt;
  float* Y = (yy == 0) ? A2 : (yy == 1) ? M2 : M1;
  bf16x8 B[2][4];
  load_bfrags(Wt, wave, lane, B);
  #pragma unroll
  for (int i = 0; i < 8; ++i) {
    int f = t + i*256, row = f >> 5, c4 = f & 31;
    int gr = tile0 + row;
    float4 v = make_float4(0.f,0.f,0.f,0.f);
    if (gr < mrows) v = *(const float4*)(X + (size_t)gr*128 + c4*4);
    *(uint2*)(Xs + row*XS_PAD + c4*4) = make_uint2(pack2(v.x,v.y), pack2(v.z,v.w));
  }
  __syncthreads();
  f32x4 acc[4][2]; zero_acc(acc);
  mfma_layer(Xs, B, lane, acc);
  #pragma unroll
  for (int rg = 0; rg < 4; ++rg)
    #pragma unroll
    for (int ctl = 0; ctl < 2; ++ctl) {
      int col = (wave*2 + ctl)*16 + lcol;
      float badd = 0.f;
      if (yy == 0) badd = b1[col];              // fold g2b1 into A2
      #pragma unroll
      for (int reg = 0; reg < 4; ++reg) {
        int gr = tile0 + rg*16 + quad*4 + reg;
        if (gr < mrows) Y[(size_t)gr*128 + col] = acc[rg][ctl][reg] + badd;
      }
    }
}

// ---------------- single-block scan (chunked, M<=2048 per chunk) ----------------
__global__ __launch_bounds__(1024) void scan_all(const int* __restrict__ counts,
                                                 int* __restrict__ row_start,
                                                 int* __restrict__ cursor, int M) {
  __shared__ int s[1024];
  __shared__ int carry_s;
  const int t = threadIdx.x;
  if (t == 0) carry_s = 0;
  __syncthreads();
  for (int base = 0; base < M; base += 2048) {
    int i0 = base + 2*t, i1 = i0 + 1;
    int c0 = (i0 < M) ? counts[i0] : 0;
    int c1 = (i1 < M) ? counts[i1] : 0;
    int pair = c0 + c1;
    s[t] = pair; __syncthreads();
    for (int off = 1; off < 1024; off <<= 1) {
      int x = (t >= off) ? s[t-off] : 0; __syncthreads();
      s[t] += x; __syncthreads();
    }
    int carry = carry_s;
    int excl = carry + s[t] - pair;
    if (i0 < M) { row_start[i0] = excl;       cursor[i0] = excl; }
    if (i1 < M) { row_start[i1] = excl + c0;  cursor[i1] = excl + c0; }
    __syncthreads();
    if (t == 1023) carry_s = carry + s[1023];
    __syncthreads();
  }
}

// -------- fill: packed 16B records {src, evec0..2} in CSR order --------
__global__ void fill_kernel(const int* __restrict__ dst, const int* __restrict__ src,
                            const float* __restrict__ evec, int* __restrict__ cursor,
                            float4* __restrict__ edata, int E) {
  int e = blockIdx.x*256 + threadIdx.x;
  if (e < E) {
    int p = atomicAdd(&cursor[dst[e]], 1);
    edata[p] = make_float4(__int_as_float(src[e]),
                           evec[(size_t)e*3], evec[(size_t)e*3+1], evec[(size_t)e*3+2]);
  }
}

// ---------------- edge phase: grid = M, one block per node ----------------
__global__ __launch_bounds__(256) void edge_mfma(
    const float* __restrict__ A2, const float* __restrict__ M2,
    const float* __restrict__ meta, const float4* __restrict__ edata,
    const int* __restrict__ row_start, const int* __restrict__ counts,
    const float* __restrict__ g2W1full,
    const unsigned short* __restrict__ W2t, const float* __restrict__ b2,
    float* __restrict__ SUM) {
  const int n = blockIdx.x;
  const int cnt = counts[n];
  if (cnt <= 0) return;                    // SUM[n] never read when count==0
  const int rs = row_start[n];

  __shared__ __align__(16) unsigned short Xh[64*XS_PAD];
  __shared__ int srcl[64];
  __shared__ float evl[192];
  const int t = threadIdx.x, lane = t & 63, wave = t >> 6;
  const int quad = lane >> 4, lcol = lane & 15;
  const int c0 = (t & 31) * 4, rbase = t >> 5;

  // prefetch first tile's records — one coalesced float4 per edge
  float4 ed = make_float4(0.f,0.f,0.f,0.f);
  if (t < 64 && t < cnt) ed = edata[rs + t];

  bf16x8 BW2[2][4];
  load_bfrags(W2t, wave, lane, BW2);
  float4 base = *(const float4*)(A2 + (size_t)n*128 + c0);   // g2b1 pre-folded
  float4 w0 = *(const float4*)(g2W1full + 256*128 + c0);
  float4 w1 = *(const float4*)(g2W1full + 257*128 + c0);
  float4 w2 = *(const float4*)(g2W1full + 258*128 + c0);
  const int colA = wave*32 + lcol, colB = colA + 16;
  const float b2A = b2[colA], b2B = b2[colB];
  float psA = 0.f, psB = 0.f;

  for (int t0 = 0; t0 < cnt; t0 += 64) {
    if (t0) __syncthreads();               // prev tile fully consumed
    if (t < 64) {
      srcl[t] = __float_as_int(ed.x);
      evl[3*t] = ed.y; evl[3*t+1] = ed.z; evl[3*t+2] = ed.w;
      int idx = t0 + 64 + t;               // prefetch next tile
      ed = make_float4(0.f,0.f,0.f,0.f);
      if (idx < cnt) ed = edata[rs + idx];
    }
    __syncthreads();
    // hoist meta-psum gathers: depend only on srcl, hidden under h+MFMA
    float mvA[16], mvB[16];
    #pragma unroll
    for (int rg = 0; rg < 4; ++rg)
      #pragma unroll
      for (int reg = 0; reg < 4; ++reg) {
        int k = rg*4 + reg, rl = rg*16 + quad*4 + reg;
        int s = srcl[rl];                  // s==0 for pad rows: loads valid
        mvA[k] = meta[(size_t)s*128 + colA];
        mvB[k] = meta[(size_t)s*128 + colB];
      }
    #pragma unroll
    for (int i = 0; i < 8; ++i) {          // h = relu(base + M2[src] + evec.Wc)
      int row = rbase + 8*i;
      float4 h = make_float4(0.f,0.f,0.f,0.f);
      if (t0 + row < cnt) {
        int s = srcl[row];
        float4 m = *(const float4*)(M2 + (size_t)s*128 + c0);
        float e0 = evl[3*row], e1 = evl[3*row+1], e2 = evl[3*row+2];
        h.x = fmaxf(base.x + m.x + e0*w0.x + e1*w1.x + e2*w2.x, 0.f);
        h.y = fmaxf(base.y + m.y + e0*w0.y + e1*w1.y + e2*w2.y, 0.f);
        h.z = fmaxf(base.z + m.z + e0*w0.z + e1*w1.z + e2*w2.z, 0.f);
        h.w = fmaxf(base.w + m.w + e0*w0.w + e1*w1.w + e2*w2.w, 0.f);
      }
      *(uint2*)(Xh + row*XS_PAD + c0) = make_uint2(pack2(h.x,h.y), pack2(h.z,h.w));
    }
    __syncthreads();
    f32x4 acc[4][2]; zero_acc(acc);
    mfma_layer(Xh, BW2, lane, acc);        // g = h @ g2W2
    #pragma unroll
    for (int rg = 0; rg < 4; ++rg)         // psum += (g+b2)*meta[src] (prefetched)
      #pragma unroll
      for (int reg = 0; reg < 4; ++reg) {
        int k = rg*4 + reg, rl = rg*16 + quad*4 + reg;
        if (t0 + rl < cnt) {
          psA += (acc[rg][0][reg] + b2A) * mvA[k];
          psB += (acc[rg][1][reg] + b2B) * mvB[k];
        }
      }
  }
  psA += __shfl_xor(psA, 16, 64); psA += __shfl_xor(psA, 32, 64);
  psB += __shfl_xor(psB, 16, 64); psB += __shfl_xor(psB, 32, 64);
  if (quad == 0) {                         // block owns node n: plain store
    SUM[(size_t)n*128 + colA] = psA;
    SUM[(size_t)n*128 + colB] = psB;
  }
}

// ------- fused node: TWO tiles per block, shared barrier structure -------
__global__ __launch_bounds__(256, 4) void fused_node2(
    const float* __restrict__ res, const float* __restrict__ meta,
    const int* __restrict__ sec_ids, const float* __restrict__ pe,
    const float* __restrict__ g1W1full, const float* __restrict__ M1,
    const unsigned short* __restrict__ g1At,
    const unsigned short* __restrict__ g1W2t, const float* __restrict__ g1b1,
    const float* __restrict__ g1b2,
    const unsigned short* __restrict__ fW1t, const float* __restrict__ fb1v,
    const unsigned short* __restrict__ fW2t, const float* __restrict__ fb2v,
    const float* __restrict__ SUM, const int* __restrict__ counts, int msize,
    float* __restrict__ out, int rows) {
  __shared__ __align__(16) unsigned short XsA[64*XS_PAD];
  __shared__ __align__(16) unsigned short XsB[64*XS_PAD];
  __shared__ int   sids[128];
  __shared__ float pel[384];
  __shared__ float inv[128];
  const int t = threadIdx.x, lane = t & 63, wave = t >> 6;
  const int quad = lane >> 4, lcol = lane & 15;
  const int base = blockIdx.x * 128;       // tileA rows [base,base+64), tileB +64
  const int c0 = (t & 31) * 4, rbase = t >> 5;
  const int colA = wave*32 + lcol, colB = colA + 16;

  if (t < 128) {
    int gr = base + t;
    sids[t] = (gr < rows) ? sec_ids[gr] : 0;
    float p0=0.f,p1=0.f,p2=0.f;
    if (gr < rows){ p0=pe[(size_t)gr*3]; p1=pe[(size_t)gr*3+1]; p2=pe[(size_t)gr*3+2]; }
    pel[3*t]=p0; pel[3*t+1]=p1; pel[3*t+2]=p2;
    int c = (gr < rows && gr < msize) ? counts[gr] : 0;
    inv[t] = (c > 0) ? 1.f/(float)c : 0.f;
  }
  bf16x8 BF[2][4];
  load_bfrags(g1At, wave, lane, BF);
  #pragma unroll
  for (int i = 0; i < 8; ++i) {                           // stage resA
    int row = rbase + 8*i, gr = base + row;
    float4 v = make_float4(0.f,0.f,0.f,0.f);
    if (gr < rows) v = *(const float4*)(res + (size_t)gr*128 + c0);
    *(uint2*)(XsA + row*XS_PAD + c0) = make_uint2(pack2(v.x,v.y), pack2(v.z,v.w));
  }
  #pragma unroll
  for (int i = 0; i < 8; ++i) {                           // stage resB
    int row = rbase + 8*i, gr = base + 64 + row;
    float4 v = make_float4(0.f,0.f,0.f,0.f);
    if (gr < rows) v = *(const float4*)(res + (size_t)gr*128 + c0);
    *(uint2*)(XsB + row*XS_PAD + c0) = make_uint2(pack2(v.x,v.y), pack2(v.z,v.w));
  }
  __syncthreads();                                        // B1: staged + sids
  f32x4 accA[4][2], accB[4][2];
  zero_acc(accA); zero_acc(accB);
  mfma_layer(XsA, BF, lane, accA);                        // resA @ g1A
  mfma_layer(XsB, BF, lane, accB);                        // resB @ g1A
  load_bfrags(g1W2t, wave, lane, BF);
  __syncthreads();                                        // B2: Xs consumed
  {
    // h1 = relu(acc + M1[sec] + b1 - pe.Wc)  (both tiles; gathers overlap)
    const float b1A = g1b1[colA], b1B = g1b1[colB];
    const float wA0 = g1W1full[256*128+colA], wA1 = g1W1full[257*128+colA],
                wA2 = g1W1full[258*128+colA];
    const float wB0 = g1W1full[256*128+colB], wB1 = g1W1full[257*128+colB],
                wB2 = g1W1full[258*128+colB];
    #pragma unroll
    for (int rg = 0; rg < 4; ++rg)
      #pragma unroll
      for (int reg = 0; reg < 4; ++reg) {
        int row = rg*16 + quad*4 + reg;
        int sid = sids[row];
        float m1A = M1[(size_t)sid*128 + colA];
        float m1B = M1[(size_t)sid*128 + colB];
        float p0 = pel[3*row], p1 = pel[3*row+1], p2 = pel[3*row+2];
        float vA = accA[rg][0][reg] + m1A + b1A - p0*wA0 - p1*wA1 - p2*wA2;
        float vB = accA[rg][1][reg] + m1B + b1B - p0*wB0 - p1*wB1 - p2*wB2;
        XsA[row*XS_PAD + colA] = f2bf(fmaxf(vA, 0.f));
        XsA[row*XS_PAD + colB] = f2bf(fmaxf(vB, 0.f));
      }
    #pragma unroll
    for (int rg = 0; rg < 4; ++rg)
      #pragma unroll
      for (int reg = 0; reg < 4; ++reg) {
        int row = rg*16 + quad*4 + reg, rr = 64 + row;
        int sid = sids[rr];
        float m1A = M1[(size_t)sid*128 + colA];
        float m1B = M1[(size_t)sid*128 + colB];
        float p0 = pel[3*rr], p1 = pel[3*rr+1], p2 = pel[3*rr+2];
        float vA = accB[rg][0][reg] + m1A + b1A - p0*wA0 - p1*wA1 - p2*wA2;
        float vB = accB[rg][1][reg] + m1B + b1B - p0*wB0 - p1*wB1 - p2*wB2;
        XsB[row*XS_PAD + colA] = f2bf(fmaxf(vA, 0.f));
        XsB[row*XS_PAD + colB] = f2bf(fmaxf(vB, 0.f));
      }
  }
  __syncthreads();                                        // B3: h1 staged
  zero_acc(accA); zero_acc(accB);
  mfma_layer(XsA, BF, lane, accA);                        // g = h1 @ g1W2
  mfma_layer(XsB, BF, lane, accB);
  load_bfrags(fW1t, wave, lane, BF);
  __syncthreads();                                        // B4: Xs consumed
  {
    const float b2A = g1b2[colA], b2B = g1b2[colB];
    #pragma unroll
    for (int rg = 0; rg < 4; ++rg)     // fuse tileA
      #pragma unroll
      for (int reg = 0; reg < 4; ++reg) {
        int row = rg*16 + quad*4 + reg, gr = base + row;
        unsigned short oA = 0, oB = 0;
        if (gr < rows) {
          int sid = sids[row];
          float gA = accA[rg][0][reg] + b2A, gB = accA[rg][1][reg] + b2B;
          float mA = meta[(size_t)sid*128 + colA], mB = meta[(size_t)sid*128 + colB];
          float rA = res[(size_t)gr*128 + colA],  rB = res[(size_t)gr*128 + colB];
          float iv = inv[row];
          float sA = 0.f, sB = 0.f;
          if (iv > 0.f) {
            sA = SUM[(size_t)gr*128 + colA] * iv;
            sB = SUM[(size_t)gr*128 + colB] * iv;
          }
          oA = f2bf(rA + gA*mA + sA);
          oB = f2bf(rB + gB*mB + sB);
        }
        XsA[row*XS_PAD + colA] = oA;
        XsA[row*XS_PAD + colB] = oB;
      }
    #pragma unroll
    for (int rg = 0; rg < 4; ++rg)     // fuse tileB
      #pragma unroll
      for (int reg = 0; reg < 4; ++reg) {
        int row = rg*16 + quad*4 + reg, rr = 64 + row, gr = base + rr;
        unsigned short oA = 0, oB = 0;
        if (gr < rows) {
          int sid = sids[rr];
          float gA = accB[rg][0][reg] + b2A, gB = accB[rg][1][reg] + b2B;
          float mA = meta[(size_t)sid*128 + colA], mB = meta[(size_t)sid*128 + colB];
          float rA = res[(size_t)gr*128 + colA],  rB = res[(size_t)gr*128 + colB];
          float iv = inv[rr];
          float sA = 0.f, sB = 0.f;
          if (iv > 0.f) {
            sA = SUM[(size_t)gr*128 + colA] * iv;
            sB = SUM[(size_t)gr*128 + colB] * iv;
          }
          oA = f2bf(rA + gA*mA + sA);
          oB = f2bf(rB + gB*mB + sB);
        }
        XsB[row*XS_PAD + colA] = oA;
        XsB[row*XS_PAD + colB] = oB;
      }
  }
  __syncthreads();                                        // B5: fused staged
  zero_acc(accA); zero_acc(accB);
  mfma_layer(XsA, BF, lane, accA);                        // fused @ fW1
  mfma_layer(XsB, BF, lane, accB);
  load_bfrags(fW2t, wave, lane, BF);
  __syncthreads();                                        // B6: Xs consumed
  {
    const float fb1A = fb1v[colA], fb1B = fb1v[colB];
    #pragma unroll
    for (int rg = 0; rg < 4; ++rg)                        // h2 both tiles
      #pragma unroll
      for (int reg = 0; reg < 4; ++reg) {
        int row = rg*16 + quad*4 + reg;
        XsA[row*XS_PAD + colA] = f2bf(fmaxf(accA[rg][0][reg] + fb1A, 0.f));
        XsA[row*XS_PAD + colB] = f2bf(fmaxf(accA[rg][1][reg] + fb1B, 0.f));
        XsB[row*XS_PAD + colA] = f2bf(fmaxf(accB[rg][0][reg] + fb1A, 0.f));
        XsB[row*XS_PAD + colB] = f2bf(fmaxf(accB[rg][1][reg] + fb1B, 0.f));
      }
  }
  __syncthreads();                                        // B7: h2 staged
  zero_acc(accA); zero_acc(accB);
  mfma_layer(XsA, BF, lane, accA);                        // out = h2 @ fW2
  mfma_layer(XsB, BF, lane, accB);
  {
    const float fb2A = fb2v[colA], fb2B = fb2v[colB];
    #pragma unroll
    for (int rg = 0; rg < 4; ++rg)                        // stores, both tiles
      #pragma unroll
      for (int reg = 0; reg < 4; ++reg) {
        int row = rg*16 + quad*4 + reg;
        int grA = base + row, grB = base + 64 + row;
        if (grA < rows) {
          out[(size_t)grA*128 + colA] = accA[rg][0][reg] + fb2A;
          out[(size_t)grA*128 + colB] = accA[rg][1][reg] + fb2B;
        }
        if (grB < rows) {
          out[(size_t)grB*128 + colA] = accB[rg][0][reg] + fb2A;
          out[(size_t)grB*128 + colB] = accB[rg][1][reg] + fb2B;
        }
      }
  }
}

extern "C" void kernel_launch(void* const* d_in, const int* in_sizes, int n_in,
                              void* d_out, int out_size, void* d_ws, size_t ws_size,
                              hipStream_t stream) {
  const float* res     = (const float*)d_in[0];
  const float* meta    = (const float*)d_in[1];
  const int*   sec_ids = (const int*)  d_in[2];
  const float* pe      = (const float*)d_in[3];
  const int*   edge    = (const int*)  d_in[4];
  const float* evec    = (const float*)d_in[5];
  const float* g1W1 = (const float*)d_in[6];
  const float* g1b1 = (const float*)d_in[7];
  const float* g1W2 = (const float*)d_in[8];
  const float* g1b2 = (const float*)d_in[9];
  const float* g2W1 = (const float*)d_in[10];
  const float* g2b1 = (const float*)d_in[11];
  const float* g2W2 = (const float*)d_in[12];
  const float* g2b2 = (const float*)d_in[13];
  const float* fW1  = (const float*)d_in[14];
  const float* fb1  = (const float*)d_in[15];
  const float* fW2  = (const float*)d_in[16];
  const float* fb2  = (const float*)d_in[17];

  const int N = in_sizes[0] / 128;
  const int M = in_sizes[1] / 128;
  const int E = in_sizes[4] / 2;
  const int* src = edge;
  const int* dst = edge + E;

  float* ws = (float*)d_ws;
  float* A2   = ws;                          // M*128
  float* M2   = A2 + (size_t)M*128;          // M*128
  float* M1   = M2 + (size_t)M*128;          // M*128 (meta @ g1B, f32)
  float* SUMb = M1 + (size_t)M*128;          // M*128 (read only when count>0)
  int* counts     = (int*)(SUMb + (size_t)M*128);
  int* row_startp = counts + M;
  int* cursor     = row_startp + M;
  uintptr_t ap = (uintptr_t)(cursor + M);
  ap = (ap + 15) & ~(uintptr_t)15;
  float4* edata = (float4*)ap;               // E x 16B packed records
  uintptr_t wp = (uintptr_t)(edata + E);
  wp = (wp + 15) & ~(uintptr_t)15;
  unsigned short* Wt = (unsigned short*)wp;  // 8 slabs x 16384
  unsigned short* W_g1A  = Wt + 0*16384;
  unsigned short* W_g1B  = Wt + 1*16384;
  unsigned short* W_g1W2 = Wt + 2*16384;
  unsigned short* W_g2A  = Wt + 3*16384;
  unsigned short* W_g2B  = Wt + 4*16384;
  unsigned short* W_g2W2 = Wt + 5*16384;
  unsigned short* W_fW1  = Wt + 6*16384;
  unsigned short* W_fW2  = Wt + 7*16384;
  float* out = (float*)d_out;

  WPtrs p;
  p.s[0] = g1W1;            p.s[1] = g1W1 + 128*128;  p.s[2] = g1W2;
  p.s[3] = g2W1;            p.s[4] = g2W1 + 128*128;  p.s[5] = g2W2;
  p.s[6] = fW1;             p.s[7] = fW2;

  const int nbMt   = (M + 63) / 64;
  const int nbN    = (N + 63) / 64;
  const int nbN2   = (nbN + 1) / 2;          // 2 tiles per block
  const int nbE    = (E + 255) / 256;
  const int nbPrep = 3*nbMt;                 // A2, M2, M1 slabs

  // 1: W transposes + zero counts
  transpose_w8<<<128, 256, 0, stream>>>(p, Wt, counts, M);
  // 2: A2/M2/M1 prep + histogram
  prep_and_hist<<<nbPrep + nbE, 256, 0, stream>>>(res, meta, W_g2A, W_g2B, W_g1B,
                                                  g2b1, A2, M2, M1, M, nbPrep,
                                                  dst, counts, E);
  // 3: scan (single block)
  scan_all<<<1, 1024, 0, stream>>>(counts, row_startp, cursor, M);
  // 4: packed CSR edge records
  fill_kernel<<<nbE, 256, 0, stream>>>(dst, src, evec, cursor, edata, E);
  // 5: edge phase — one block per node, no atomics
  edge_mfma<<<M, 256, 0, stream>>>(A2, M2, meta, edata, row_startp, counts,
                                   g2W1, W_g2W2, g2b2, SUMb);
  // 6: fused node path — two tiles per block
  fused_node2<<<nbN2, 256, 0, stream>>>(res, meta, sec_ids, pe, g1W1, M1,
                                        W_g1A, W_g1W2, g1b1, g1b2,
                                        W_fW1, fb1, W_fW2, fb2,
                                        SUMb, counts, M, out, N);
}